// Round 4
// baseline (648.314 us; speedup 1.0000x reference)
//
#include <hip/hip_runtime.h>
#include <math.h>

#define D_MODEL 1024
#define NHEAD   16
#define HDIM    64
#define SEQ     2048
#define BATCH   4
#define NROWS   (BATCH*SEQ)   // 8192

using bf16x8 = __attribute__((ext_vector_type(8))) short;
using bf16x4 = __attribute__((ext_vector_type(4))) short;
using f32x4  = __attribute__((ext_vector_type(4))) float;

__device__ __forceinline__ unsigned short f2bf(float f) {
    unsigned u = __float_as_uint(f);
    u += 0x7fffu + ((u >> 16) & 1u);
    return (unsigned short)(u >> 16);
}

#define ASYNC_COPY16(g, l) \
    __builtin_amdgcn_global_load_lds((__attribute__((address_space(1))) const void*)(g), \
                                     (__attribute__((address_space(3))) void*)(l), 16, 0, 0)

// ---------------- LayerNorm: one block (256 thr) per row of 1024 ----------------
__global__ __launch_bounds__(256) void ln_kernel(const float* __restrict__ x,
                                                 const float* __restrict__ g,
                                                 const float* __restrict__ b,
                                                 unsigned short* __restrict__ out) {
    const int row = blockIdx.x;
    const int tid = threadIdx.x;
    const float4* x4 = (const float4*)(x + (size_t)row * D_MODEL);
    float4 v = x4[tid];
    float s  = v.x + v.y + v.z + v.w;
    float sq = v.x*v.x + v.y*v.y + v.z*v.z + v.w*v.w;
    #pragma unroll
    for (int off = 32; off >= 1; off >>= 1) {
        s  += __shfl_down(s,  off, 64);
        sq += __shfl_down(sq, off, 64);
    }
    __shared__ float rs[4], rq[4];
    const int wave = tid >> 6;
    if ((tid & 63) == 0) { rs[wave] = s; rq[wave] = sq; }
    __syncthreads();
    const float tot  = rs[0] + rs[1] + rs[2] + rs[3];
    const float totq = rq[0] + rq[1] + rq[2] + rq[3];
    const float mu   = tot * (1.0f / D_MODEL);
    const float var  = totq * (1.0f / D_MODEL) - mu * mu;
    const float rstd = rsqrtf(var + 1e-5f);
    const float4 gv = ((const float4*)g)[tid];
    const float4 bv = ((const float4*)b)[tid];
    unsigned short* o = out + (size_t)row * D_MODEL + tid * 4;
    o[0] = f2bf((v.x - mu) * rstd * gv.x + bv.x);
    o[1] = f2bf((v.y - mu) * rstd * gv.y + bv.y);
    o[2] = f2bf((v.z - mu) * rstd * gv.z + bv.z);
    o[3] = f2bf((v.w - mu) * rstd * gv.w + bv.w);
}

// ------------- Weight transpose+convert: w[K][N] f32 -> wt[N][K] bf16 -----------
__global__ __launch_bounds__(256) void wt_kernel(const float* __restrict__ w,
                                                 unsigned short* __restrict__ wt,
                                                 int K, int N) {
    __shared__ float tile[32][33];
    const int n0 = blockIdx.x * 32, k0 = blockIdx.y * 32;
    const int tx = threadIdx.x & 31, ty = threadIdx.x >> 5;
    #pragma unroll
    for (int j = 0; j < 4; ++j)
        tile[ty + j * 8][tx] = w[(size_t)(k0 + ty + j * 8) * N + n0 + tx];
    __syncthreads();
    #pragma unroll
    for (int j = 0; j < 4; ++j)
        wt[(size_t)(n0 + ty + j * 8) * K + k0 + tx] = f2bf(tile[tx][ty + j * 8]);
}

// ------------- GEMM: C[M,N] = A[M,K] * Bt[N,K]^T,  BK=64, 128x128 tile ----------
// 256 thr = 4 waves (2x2), each wave 64x64 = 4x4 MFMAs x 2 k-halves.
// 8-chunk XOR swizzle: physical chunk p of row r holds global chunk p ^ (r&7).
// ATOMIC: f32 atomicAdd epilogue for split-K (bias added by z==0 only, no resid).
template<bool GELU, bool OUT_BF16, bool QSCALE, bool ATOMIC>
__global__ __launch_bounds__(256) void gemm_bt(const unsigned short* __restrict__ A,
                                               const unsigned short* __restrict__ Bt,
                                               const float* __restrict__ bias,
                                               const float* __restrict__ resid,
                                               void* __restrict__ outp,
                                               int M, int N, int K, int Ksplit) {
    __shared__ __align__(16) unsigned short As[128 * 64];
    __shared__ __align__(16) unsigned short Bs[128 * 64];

    const int tid  = threadIdx.x;
    const int lane = tid & 63;
    const int wave = __builtin_amdgcn_readfirstlane(tid >> 6);
    const int quad = lane >> 4, l16 = lane & 15;
    const int wm = wave >> 1, wn = wave & 1;
    const int m0 = blockIdx.y * 128, n0 = blockIdx.x * 128;

    f32x4 acc[4][4] = {};

    // staging: 4 issues per matrix; issue i covers rows i*32 + (tid>>3), chunk tid&7
    const int rAl = tid >> 3;                    // 0..31
    const int p   = tid & 7;
    const int gch = (p ^ (rAl & 7)) * 8;         // swizzled global chunk (elements)

    const int kbeg = ATOMIC ? blockIdx.z * Ksplit : 0;
    const int kend = kbeg + Ksplit;

    const unsigned short* Ag[4];
    const unsigned short* Bg[4];
    #pragma unroll
    for (int i = 0; i < 4; ++i) {
        Ag[i] = A  + (size_t)(m0 + i * 32 + rAl) * K + gch + kbeg;
        Bg[i] = Bt + (size_t)(n0 + i * 32 + rAl) * K + gch + kbeg;
    }

    // read-side: physical chunk offset for k-half 0 (elements); half 1 = pc ^ 32
    const int pc = (quad ^ (l16 & 7)) * 8;

    for (int kb = 0; kb < kend - kbeg; kb += 64) {
        #pragma unroll
        for (int i = 0; i < 4; ++i) {
            ASYNC_COPY16(Ag[i] + kb, As + i * 2048 + tid * 8);
            ASYNC_COPY16(Bg[i] + kb, Bs + i * 2048 + tid * 8);
        }
        __syncthreads();

        #pragma unroll
        for (int half = 0; half < 2; ++half) {
            const int off = half ? (pc ^ 32) : pc;
            bf16x8 a[4], b[4];
            #pragma unroll
            for (int i = 0; i < 4; ++i)
                a[i] = *(const bf16x8*)&As[(wm * 64 + i * 16 + l16) * 64 + off];
            #pragma unroll
            for (int j = 0; j < 4; ++j)
                b[j] = *(const bf16x8*)&Bs[(wn * 64 + j * 16 + l16) * 64 + off];
            #pragma unroll
            for (int i = 0; i < 4; ++i)
                #pragma unroll
                for (int j = 0; j < 4; ++j)
                    acc[i][j] = __builtin_amdgcn_mfma_f32_16x16x32_bf16(a[i], b[j], acc[i][j], 0, 0, 0);
        }
        __syncthreads();
    }

    #pragma unroll
    for (int i = 0; i < 4; ++i)
      #pragma unroll
      for (int j = 0; j < 4; ++j)
        #pragma unroll
        for (int r = 0; r < 4; ++r) {
            const int row = m0 + wm * 64 + i * 16 + quad * 4 + r;
            const int col = n0 + wn * 64 + j * 16 + l16;
            float v = acc[i][j][r];
            if (ATOMIC) {
                if (bias && blockIdx.z == 0) v += bias[col];
                atomicAdd(&((float*)outp)[(size_t)row * N + col], v);
            } else {
                if (QSCALE && col < 1024) v *= 0.125f;
                if (bias) v += bias[col];
                if (GELU) {
                    const float u = 0.7978845608028654f * (v + 0.044715f * v * v * v);
                    const float e = __expf(2.0f * u);
                    v = 0.5f * v * (2.0f - 2.0f / (e + 1.0f));
                }
                if (resid) v += resid[(size_t)row * N + col];
                if (OUT_BF16) ((unsigned short*)outp)[(size_t)row * N + col] = f2bf(v);
                else          ((float*)outp)[(size_t)row * N + col] = v;
            }
        }
}

// ---------------- Flash attention, causal, balanced (paired 128-q tiles) --------
__global__ __launch_bounds__(256) void attn_kernel(const unsigned short* __restrict__ qk,
                                                   const unsigned short* __restrict__ VT,
                                                   unsigned short* __restrict__ y) {
    __shared__ __align__(16) unsigned short Qs[128 * 64];
    __shared__ __align__(16) unsigned short Ks[64 * 64];
    __shared__ __align__(16) unsigned short Vs[80 * 64];   // rows 64..79: ones block
    __shared__ __align__(16) unsigned short Ps[128 * 68];

    const int tid  = threadIdx.x;
    const int lane = tid & 63, w = tid >> 6;
    const int quad = lane >> 4, l16 = lane & 15;
    const int s7   = l16 & 7;
    const int pc0  = (quad ^ s7) * 8;
    const int pc1  = ((quad + 4) ^ s7) * 8;
    const int srow = tid >> 3, sp = tid & 7;

    const int pairidx = blockIdx.x;          // 0..7
    const int bh = blockIdx.y;
    const int b = bh >> 4, h = bh & 15;
    const size_t rowbase = (size_t)b * SEQ;
    const unsigned short* Qbase = qk + h * 64;
    const unsigned short* Kbase = qk + 1024 + h * 64;
    const unsigned short* Vbase = VT + (size_t)(h * 64) * NROWS + b * SEQ;

    #pragma unroll
    for (int e = 0; e < 4; ++e) {
        const int off = tid * 4 + e;
        Vs[4096 + off] = (off < 64) ? (unsigned short)0x3F80 : (unsigned short)0;
    }

    for (int phase = 0; phase < 2; ++phase) {
        const int Q = phase ? pairidx : (15 - pairidx);
        const int nkt = 2 * Q + 2;
        const int qg0 = Q * 128;

        #pragma unroll
        for (int i = 0; i < 4; ++i) {
            const int row = i * 32 + srow;
            const int c = sp ^ (row & 7);
            ASYNC_COPY16(Qbase + (rowbase + qg0 + row) * 2048 + c * 8,
                         (char*)Qs + i * 4096 + tid * 16);
        }
        __syncthreads();

        bf16x8 aq[2][2];
        #pragma unroll
        for (int sub = 0; sub < 2; ++sub) {
            const int qrow = sub * 64 + w * 16 + l16;
            aq[sub][0] = *(const bf16x8*)&Qs[qrow * 64 + pc0];
            aq[sub][1] = *(const bf16x8*)&Qs[qrow * 64 + pc1];
        }

        f32x4 o[2][5] = {};

        for (int kt = 0; kt < nkt; ++kt) {
            #pragma unroll
            for (int i = 0; i < 2; ++i) {
                const int row = i * 32 + srow;
                const int c = sp ^ (row & 7);
                ASYNC_COPY16(Kbase + (rowbase + kt * 64 + row) * 2048 + c * 8,
                             (char*)Ks + i * 4096 + tid * 16);
                ASYNC_COPY16(Vbase + (size_t)row * NROWS + kt * 64 + c * 8,
                             (char*)Vs + i * 4096 + tid * 16);
            }
            __syncthreads();

            bf16x8 bk[4][2];
            #pragma unroll
            for (int cb = 0; cb < 4; ++cb) {
                const int krow = cb * 16 + l16;
                bk[cb][0] = *(const bf16x8*)&Ks[krow * 64 + pc0];
                bk[cb][1] = *(const bf16x8*)&Ks[krow * 64 + pc1];
            }

            #pragma unroll
            for (int sub = 0; sub < 2; ++sub) {
                if (kt > 2 * Q + sub) continue;
                f32x4 s[4] = {};
                #pragma unroll
                for (int cb = 0; cb < 4; ++cb) {
                    s[cb] = __builtin_amdgcn_mfma_f32_16x16x32_bf16(aq[sub][0], bk[cb][0], s[cb], 0, 0, 0);
                    s[cb] = __builtin_amdgcn_mfma_f32_16x16x32_bf16(aq[sub][1], bk[cb][1], s[cb], 0, 0, 0);
                }
                const int prow0 = sub * 64 + w * 16 + quad * 4;
                if (kt == 2 * Q + sub) {
                    const int qg = qg0 + prow0;
                    const int kg = kt * 64 + l16;
                    #pragma unroll
                    for (int cb = 0; cb < 4; ++cb)
                        #pragma unroll
                        for (int r = 0; r < 4; ++r) {
                            const float e = __expf(s[cb][r]);
                            const float pv = (kg + cb * 16 > qg + r) ? 0.0f : e;
                            Ps[(prow0 + r) * 68 + cb * 16 + l16] = f2bf(pv);
                        }
                } else {
                    #pragma unroll
                    for (int cb = 0; cb < 4; ++cb)
                        #pragma unroll
                        for (int r = 0; r < 4; ++r)
                            Ps[(prow0 + r) * 68 + cb * 16 + l16] = f2bf(__expf(s[cb][r]));
                }
            }
            __syncthreads();

            bf16x8 bv[5][2];
            #pragma unroll
            for (int db = 0; db < 5; ++db) {
                const int vrow = db * 16 + l16;
                bv[db][0] = *(const bf16x8*)&Vs[vrow * 64 + pc0];
                bv[db][1] = *(const bf16x8*)&Vs[vrow * 64 + pc1];
            }
            #pragma unroll
            for (int sub = 0; sub < 2; ++sub) {
                if (kt > 2 * Q + sub) continue;
                const unsigned short* pb = &Ps[(sub * 64 + w * 16 + l16) * 68];
                bf16x8 ap0, ap1;
                *(bf16x4*)&ap0       = *(const bf16x4*)(pb + quad * 8);
                *((bf16x4*)&ap0 + 1) = *(const bf16x4*)(pb + quad * 8 + 4);
                *(bf16x4*)&ap1       = *(const bf16x4*)(pb + 32 + quad * 8);
                *((bf16x4*)&ap1 + 1) = *(const bf16x4*)(pb + 32 + quad * 8 + 4);
                #pragma unroll
                for (int db = 0; db < 5; ++db) {
                    o[sub][db] = __builtin_amdgcn_mfma_f32_16x16x32_bf16(ap0, bv[db][0], o[sub][db], 0, 0, 0);
                    o[sub][db] = __builtin_amdgcn_mfma_f32_16x16x32_bf16(ap1, bv[db][1], o[sub][db], 0, 0, 0);
                }
            }
            __syncthreads();
        }

        #pragma unroll
        for (int sub = 0; sub < 2; ++sub)
            #pragma unroll
            for (int r = 0; r < 4; ++r) {
                const float lsum = __shfl(o[sub][4][r], lane & 48);
                const float rinv = 1.0f / lsum;
                const int trow = qg0 + sub * 64 + w * 16 + quad * 4 + r;
                unsigned short* yp = y + (rowbase + trow) * (size_t)D_MODEL + h * 64 + l16;
                #pragma unroll
                for (int db = 0; db < 4; ++db)
                    yp[db * 16] = f2bf(o[sub][db][r] * rinv);
            }
    }
}

extern "C" void kernel_launch(void* const* d_in, const int* in_sizes, int n_in,
                              void* d_out, int out_size, void* d_ws, size_t ws_size,
                              hipStream_t stream) {
    (void)in_sizes; (void)n_in; (void)out_size; (void)ws_size;
    const float* x      = (const float*)d_in[0];
    const float* w_attn = (const float*)d_in[1];
    const float* w_o    = (const float*)d_in[2];
    const float* ln1_g  = (const float*)d_in[3];
    const float* ln1_b  = (const float*)d_in[4];
    const float* ln2_g  = (const float*)d_in[5];
    const float* ln2_b  = (const float*)d_in[6];
    const float* w_fc   = (const float*)d_in[7];
    const float* b_fc   = (const float*)d_in[8];
    const float* w_proj = (const float*)d_in[9];
    const float* b_proj = (const float*)d_in[10];
    float* out = (float*)d_out;

    char* ws = (char*)d_ws;
    unsigned short* ln_buf = (unsigned short*)ws;                           // 16 MiB
    unsigned short* qkbuf  = (unsigned short*)(ws + (size_t)16  * 1048576); // 32 MiB
    unsigned short* VTbuf  = (unsigned short*)(ws + (size_t)48  * 1048576); // 16 MiB
    unsigned short* hbuf   = (unsigned short*)(ws + (size_t)64  * 1048576); // 64 MiB
    unsigned short* wt_attn = hbuf;                                         // 6 MiB
    unsigned short* wt_o    = hbuf + (size_t)3072 * 1024;                   // 2 MiB
    unsigned short* wt_fc   = qkbuf;                                        // 8 MiB
    unsigned short* wt_proj = qkbuf + (size_t)4096 * 1024;                  // 8 MiB

    wt_kernel<<<dim3(3072 / 32, 1024 / 32), 256, 0, stream>>>(w_attn, wt_attn, 1024, 3072);
    wt_kernel<<<dim3(1024 / 32, 1024 / 32), 256, 0, stream>>>(w_o, wt_o, 1024, 1024);

    ln_kernel<<<NROWS, 256, 0, stream>>>(x, ln1_g, ln1_b, ln_buf);
    // QK projection (Q pre-scaled by 1/sqrt(hd))
    gemm_bt<false, true, true, false><<<dim3(2048 / 128, NROWS / 128), 256, 0, stream>>>(
        ln_buf, wt_attn, nullptr, nullptr, qkbuf, NROWS, 2048, 1024, 1024);
    // V^T projection
    gemm_bt<false, true, false, false><<<dim3(NROWS / 128, 1024 / 128), 256, 0, stream>>>(
        wt_attn + (size_t)2048 * 1024, ln_buf, nullptr, nullptr, VTbuf, 1024, NROWS, 1024, 1024);

    attn_kernel<<<dim3(8, BATCH * NHEAD), 256, 0, stream>>>(qkbuf, VTbuf, ln_buf);

    gemm_bt<false, false, false, false><<<dim3(1024 / 128, NROWS / 128), 256, 0, stream>>>(
        ln_buf, wt_o, nullptr, x, d_out, NROWS, 1024, 1024, 1024);

    ln_kernel<<<NROWS, 256, 0, stream>>>(out, ln2_g, ln2_b, ln_buf);

    wt_kernel<<<dim3(4096 / 32, 1024 / 32), 256, 0, stream>>>(w_fc, wt_fc, 1024, 4096);
    wt_kernel<<<dim3(1024 / 32, 4096 / 32), 256, 0, stream>>>(w_proj, wt_proj, 4096, 1024);

    gemm_bt<true, true, false, false><<<dim3(4096 / 128, NROWS / 128), 256, 0, stream>>>(
        ln_buf, wt_fc, b_fc, nullptr, hbuf, NROWS, 4096, 1024, 1024);
    // proj: split-K=4, atomicAdd into d_out (which already holds x + attn residual)
    gemm_bt<false, false, false, true><<<dim3(1024 / 128, NROWS / 128, 4), 256, 0, stream>>>(
        hbuf, wt_proj, b_proj, nullptr, d_out, NROWS, 1024, 4096, 1024);
}

// Round 5
// 587.579 us; speedup vs baseline: 1.1034x; 1.1034x over previous
//
#include <hip/hip_runtime.h>
#include <math.h>

#define D_MODEL 1024
#define NHEAD   16
#define HDIM    64
#define SEQ     2048
#define BATCH   4
#define NROWS   (BATCH*SEQ)   // 8192

using bf16x8 = __attribute__((ext_vector_type(8))) short;
using bf16x4 = __attribute__((ext_vector_type(4))) short;
using f32x4  = __attribute__((ext_vector_type(4))) float;

__device__ __forceinline__ unsigned short f2bf(float f) {
    unsigned u = __float_as_uint(f);
    u += 0x7fffu + ((u >> 16) & 1u);
    return (unsigned short)(u >> 16);
}
__device__ __forceinline__ float bf2f(unsigned short h) {
    unsigned u = ((unsigned)h) << 16;
    return __uint_as_float(u);
}

#define ASYNC_COPY16(g, l) \
    __builtin_amdgcn_global_load_lds((__attribute__((address_space(1))) const void*)(g), \
                                     (__attribute__((address_space(3))) void*)(l), 16, 0, 0)

// ---------------- LayerNorm: one block (256 thr) per row of 1024 ----------------
__global__ __launch_bounds__(256) void ln_kernel(const float* __restrict__ x,
                                                 const float* __restrict__ g,
                                                 const float* __restrict__ b,
                                                 unsigned short* __restrict__ out) {
    const int row = blockIdx.x;
    const int tid = threadIdx.x;
    const float4* x4 = (const float4*)(x + (size_t)row * D_MODEL);
    float4 v = x4[tid];
    float s  = v.x + v.y + v.z + v.w;
    float sq = v.x*v.x + v.y*v.y + v.z*v.z + v.w*v.w;
    #pragma unroll
    for (int off = 32; off >= 1; off >>= 1) {
        s  += __shfl_down(s,  off, 64);
        sq += __shfl_down(sq, off, 64);
    }
    __shared__ float rs[4], rq[4];
    const int wave = tid >> 6;
    if ((tid & 63) == 0) { rs[wave] = s; rq[wave] = sq; }
    __syncthreads();
    const float tot  = rs[0] + rs[1] + rs[2] + rs[3];
    const float totq = rq[0] + rq[1] + rq[2] + rq[3];
    const float mu   = tot * (1.0f / D_MODEL);
    const float var  = totq * (1.0f / D_MODEL) - mu * mu;
    const float rstd = rsqrtf(var + 1e-5f);
    const float4 gv = ((const float4*)g)[tid];
    const float4 bv = ((const float4*)b)[tid];
    unsigned short* o = out + (size_t)row * D_MODEL + tid * 4;
    o[0] = f2bf((v.x - mu) * rstd * gv.x + bv.x);
    o[1] = f2bf((v.y - mu) * rstd * gv.y + bv.y);
    o[2] = f2bf((v.z - mu) * rstd * gv.z + bv.z);
    o[3] = f2bf((v.w - mu) * rstd * gv.w + bv.w);
}

// ------------- Weight transpose+convert: w[K][N] f32 -> wt[N][K] bf16 -----------
__global__ __launch_bounds__(256) void wt_kernel(const float* __restrict__ w,
                                                 unsigned short* __restrict__ wt,
                                                 int K, int N) {
    __shared__ float tile[32][33];
    const int n0 = blockIdx.x * 32, k0 = blockIdx.y * 32;
    const int tx = threadIdx.x & 31, ty = threadIdx.x >> 5;
    #pragma unroll
    for (int j = 0; j < 4; ++j)
        tile[ty + j * 8][tx] = w[(size_t)(k0 + ty + j * 8) * N + n0 + tx];
    __syncthreads();
    #pragma unroll
    for (int j = 0; j < 4; ++j)
        wt[(size_t)(n0 + ty + j * 8) * K + k0 + tx] = f2bf(tile[tx][ty + j * 8]);
}

// ------------- GEMM 128x128, BK=32 (m97 structure): C = A[M,K] * Bt[N,K]^T ------
// PARTIAL: split-K over blockIdx.z, plain bf16 partial to outp + z*M*N.
template<bool GELU, bool OUT_BF16, bool QSCALE, bool PARTIAL>
__global__ __launch_bounds__(256) void gemm_bt(const unsigned short* __restrict__ A,
                                               const unsigned short* __restrict__ Bt,
                                               const float* __restrict__ bias,
                                               const float* __restrict__ resid,
                                               void* __restrict__ outp,
                                               int M, int N, int K, int Kslice) {
    __shared__ __align__(16) unsigned short As[128 * 32];
    __shared__ __align__(16) unsigned short Bs[128 * 32];

    const int tid  = threadIdx.x;
    const int lane = tid & 63;
    const int wave = __builtin_amdgcn_readfirstlane(tid >> 6);
    const int quad = lane >> 4, l16 = lane & 15;
    const int wm = wave >> 1, wn = wave & 1;
    const int m0 = blockIdx.y * 128, n0 = blockIdx.x * 128;
    const int kbeg = PARTIAL ? blockIdx.z * Kslice : 0;

    f32x4 acc[4][4] = {};

    const int rA = tid >> 2;
    const int p  = tid & 3;
    const int cs = (p ^ ((rA >> 1) & 3)) * 8;

    const unsigned short* Ag0 = A  + (size_t)(m0 + rA) * K + cs + kbeg;
    const unsigned short* Ag1 = A  + (size_t)(m0 + rA + 64) * K + cs + kbeg;
    const unsigned short* Bg0 = Bt + (size_t)(n0 + rA) * K + cs + kbeg;
    const unsigned short* Bg1 = Bt + (size_t)(n0 + rA + 64) * K + cs + kbeg;
    unsigned short* Al0 = As + tid * 8;
    unsigned short* Al1 = As + tid * 8 + 2048;
    unsigned short* Bl0 = Bs + tid * 8;
    unsigned short* Bl1 = Bs + tid * 8 + 2048;

    const int sw = (quad ^ ((l16 >> 1) & 3)) * 8;

    for (int kb = 0; kb < Kslice; kb += 32) {
        ASYNC_COPY16(Ag0 + kb, Al0);
        ASYNC_COPY16(Ag1 + kb, Al1);
        ASYNC_COPY16(Bg0 + kb, Bl0);
        ASYNC_COPY16(Bg1 + kb, Bl1);
        __syncthreads();

        bf16x8 a[4], b[4];
        #pragma unroll
        for (int i = 0; i < 4; ++i)
            a[i] = *(const bf16x8*)&As[(wm * 64 + i * 16 + l16) * 32 + sw];
        #pragma unroll
        for (int j = 0; j < 4; ++j)
            b[j] = *(const bf16x8*)&Bs[(wn * 64 + j * 16 + l16) * 32 + sw];
        #pragma unroll
        for (int i = 0; i < 4; ++i)
            #pragma unroll
            for (int j = 0; j < 4; ++j)
                acc[i][j] = __builtin_amdgcn_mfma_f32_16x16x32_bf16(a[i], b[j], acc[i][j], 0, 0, 0);
        __syncthreads();
    }

    unsigned short* outb = (unsigned short*)outp;
    if (PARTIAL) outb += (size_t)blockIdx.z * M * N;

    #pragma unroll
    for (int i = 0; i < 4; ++i)
      #pragma unroll
      for (int j = 0; j < 4; ++j)
        #pragma unroll
        for (int r = 0; r < 4; ++r) {
            const int row = m0 + wm * 64 + i * 16 + quad * 4 + r;
            const int col = n0 + wn * 64 + j * 16 + l16;
            float v = acc[i][j][r];
            if (PARTIAL) {
                outb[(size_t)row * N + col] = f2bf(v);
            } else {
                if (QSCALE && col < 1024) v *= 0.125f;
                if (bias) v += bias[col];
                if (GELU) {
                    const float u = 0.7978845608028654f * (v + 0.044715f * v * v * v);
                    const float e = __expf(2.0f * u);
                    v = 0.5f * v * (2.0f - 2.0f / (e + 1.0f));
                }
                if (resid) v += resid[(size_t)row * N + col];
                if (OUT_BF16) outb[(size_t)row * N + col] = f2bf(v);
                else          ((float*)outp)[(size_t)row * N + col] = v;
            }
        }
}

// ------------- GEMM 256x128, BK=32: dense-MFMA tile for fc ----------------------
// 4 waves 2x2: wave covers 128 rows x 64 cols = 8x4 MFMAs. bias+gelu+bf16 out.
__global__ __launch_bounds__(256, 2) void gemm_big(const unsigned short* __restrict__ A,
                                                   const unsigned short* __restrict__ Bt,
                                                   const float* __restrict__ bias,
                                                   unsigned short* __restrict__ outb,
                                                   int M, int N, int K) {
    __shared__ __align__(16) unsigned short As[256 * 32];
    __shared__ __align__(16) unsigned short Bs[128 * 32];

    const int tid  = threadIdx.x;
    const int lane = tid & 63;
    const int wave = __builtin_amdgcn_readfirstlane(tid >> 6);
    const int quad = lane >> 4, l16 = lane & 15;
    const int wm = wave >> 1, wn = wave & 1;
    const int m0 = blockIdx.y * 256, n0 = blockIdx.x * 128;

    f32x4 acc[8][4] = {};

    const int rr = tid >> 2;                 // 0..63
    const int p  = tid & 3;
    const int cs = (p ^ ((rr >> 1) & 3)) * 8;

    const unsigned short* Ag[4];
    const unsigned short* Bg[2];
    #pragma unroll
    for (int i = 0; i < 4; ++i)
        Ag[i] = A + (size_t)(m0 + i * 64 + rr) * K + cs;
    #pragma unroll
    for (int i = 0; i < 2; ++i)
        Bg[i] = Bt + (size_t)(n0 + i * 64 + rr) * K + cs;

    const int sw = (quad ^ ((l16 >> 1) & 3)) * 8;

    for (int kb = 0; kb < K; kb += 32) {
        #pragma unroll
        for (int i = 0; i < 4; ++i)
            ASYNC_COPY16(Ag[i] + kb, As + i * 2048 + tid * 8);
        #pragma unroll
        for (int i = 0; i < 2; ++i)
            ASYNC_COPY16(Bg[i] + kb, Bs + i * 2048 + tid * 8);
        __syncthreads();

        bf16x8 b[4];
        #pragma unroll
        for (int j = 0; j < 4; ++j)
            b[j] = *(const bf16x8*)&Bs[(wn * 64 + j * 16 + l16) * 32 + sw];
        #pragma unroll
        for (int i = 0; i < 8; ++i) {
            bf16x8 a = *(const bf16x8*)&As[(wm * 128 + i * 16 + l16) * 32 + sw];
            #pragma unroll
            for (int j = 0; j < 4; ++j)
                acc[i][j] = __builtin_amdgcn_mfma_f32_16x16x32_bf16(a, b[j], acc[i][j], 0, 0, 0);
        }
        __syncthreads();
    }

    #pragma unroll
    for (int i = 0; i < 8; ++i)
      #pragma unroll
      for (int j = 0; j < 4; ++j)
        #pragma unroll
        for (int r = 0; r < 4; ++r) {
            const int row = m0 + wm * 128 + i * 16 + quad * 4 + r;
            const int col = n0 + wn * 64 + j * 16 + l16;
            float v = acc[i][j][r] + bias[col];
            const float u = 0.7978845608028654f * (v + 0.044715f * v * v * v);
            const float e = __expf(2.0f * u);
            v = 0.5f * v * (2.0f - 2.0f / (e + 1.0f));
            outb[(size_t)row * N + col] = f2bf(v);
        }
}

// ------------- split-K reduce: out += bias + p0 + p1 (bf16 partials) ------------
__global__ __launch_bounds__(256) void reduce_kernel(float* __restrict__ out,
                                                     const unsigned short* __restrict__ p0,
                                                     const unsigned short* __restrict__ p1,
                                                     const float* __restrict__ bias) {
    const int row = blockIdx.x;
    const int c0 = threadIdx.x * 4;
    const size_t base = (size_t)row * D_MODEL + c0;
    float4 o = *(float4*)(out + base);
    ushort4 a = *(const ushort4*)(p0 + base);
    ushort4 b = *(const ushort4*)(p1 + base);
    const float4 bs = *(const float4*)(bias + c0);
    o.x += bs.x + bf2f(a.x) + bf2f(b.x);
    o.y += bs.y + bf2f(a.y) + bf2f(b.y);
    o.z += bs.z + bf2f(a.z) + bf2f(b.z);
    o.w += bs.w + bf2f(a.w) + bf2f(b.w);
    *(float4*)(out + base) = o;
}

// ---------------- Flash attention, causal, balanced (paired 128-q tiles) --------
__global__ __launch_bounds__(256) void attn_kernel(const unsigned short* __restrict__ qk,
                                                   const unsigned short* __restrict__ VT,
                                                   unsigned short* __restrict__ y) {
    __shared__ __align__(16) unsigned short Qs[128 * 64];
    __shared__ __align__(16) unsigned short Ks[64 * 64];
    __shared__ __align__(16) unsigned short Vs[80 * 64];
    __shared__ __align__(16) unsigned short Ps[128 * 68];

    const int tid  = threadIdx.x;
    const int lane = tid & 63, w = tid >> 6;
    const int quad = lane >> 4, l16 = lane & 15;
    const int s7   = l16 & 7;
    const int pc0  = (quad ^ s7) * 8;
    const int pc1  = ((quad + 4) ^ s7) * 8;
    const int srow = tid >> 3, sp = tid & 7;

    const int pairidx = blockIdx.x;
    const int bh = blockIdx.y;
    const int b = bh >> 4, h = bh & 15;
    const size_t rowbase = (size_t)b * SEQ;
    const unsigned short* Qbase = qk + h * 64;
    const unsigned short* Kbase = qk + 1024 + h * 64;
    const unsigned short* Vbase = VT + (size_t)(h * 64) * NROWS + b * SEQ;

    #pragma unroll
    for (int e = 0; e < 4; ++e) {
        const int off = tid * 4 + e;
        Vs[4096 + off] = (off < 64) ? (unsigned short)0x3F80 : (unsigned short)0;
    }

    for (int phase = 0; phase < 2; ++phase) {
        const int Q = phase ? pairidx : (15 - pairidx);
        const int nkt = 2 * Q + 2;
        const int qg0 = Q * 128;

        #pragma unroll
        for (int i = 0; i < 4; ++i) {
            const int row = i * 32 + srow;
            const int c = sp ^ (row & 7);
            ASYNC_COPY16(Qbase + (rowbase + qg0 + row) * 2048 + c * 8,
                         (char*)Qs + i * 4096 + tid * 16);
        }
        __syncthreads();

        bf16x8 aq[2][2];
        #pragma unroll
        for (int sub = 0; sub < 2; ++sub) {
            const int qrow = sub * 64 + w * 16 + l16;
            aq[sub][0] = *(const bf16x8*)&Qs[qrow * 64 + pc0];
            aq[sub][1] = *(const bf16x8*)&Qs[qrow * 64 + pc1];
        }

        f32x4 o[2][5] = {};

        for (int kt = 0; kt < nkt; ++kt) {
            #pragma unroll
            for (int i = 0; i < 2; ++i) {
                const int row = i * 32 + srow;
                const int c = sp ^ (row & 7);
                ASYNC_COPY16(Kbase + (rowbase + kt * 64 + row) * 2048 + c * 8,
                             (char*)Ks + i * 4096 + tid * 16);
                ASYNC_COPY16(Vbase + (size_t)row * NROWS + kt * 64 + c * 8,
                             (char*)Vs + i * 4096 + tid * 16);
            }
            __syncthreads();

            bf16x8 bk[4][2];
            #pragma unroll
            for (int cb = 0; cb < 4; ++cb) {
                const int krow = cb * 16 + l16;
                bk[cb][0] = *(const bf16x8*)&Ks[krow * 64 + pc0];
                bk[cb][1] = *(const bf16x8*)&Ks[krow * 64 + pc1];
            }

            #pragma unroll
            for (int sub = 0; sub < 2; ++sub) {
                if (kt > 2 * Q + sub) continue;
                f32x4 s[4] = {};
                #pragma unroll
                for (int cb = 0; cb < 4; ++cb) {
                    s[cb] = __builtin_amdgcn_mfma_f32_16x16x32_bf16(aq[sub][0], bk[cb][0], s[cb], 0, 0, 0);
                    s[cb] = __builtin_amdgcn_mfma_f32_16x16x32_bf16(aq[sub][1], bk[cb][1], s[cb], 0, 0, 0);
                }
                const int prow0 = sub * 64 + w * 16 + quad * 4;
                if (kt == 2 * Q + sub) {
                    const int qg = qg0 + prow0;
                    const int kg = kt * 64 + l16;
                    #pragma unroll
                    for (int cb = 0; cb < 4; ++cb)
                        #pragma unroll
                        for (int r = 0; r < 4; ++r) {
                            const float e = __expf(s[cb][r]);
                            const float pv = (kg + cb * 16 > qg + r) ? 0.0f : e;
                            Ps[(prow0 + r) * 68 + cb * 16 + l16] = f2bf(pv);
                        }
                } else {
                    #pragma unroll
                    for (int cb = 0; cb < 4; ++cb)
                        #pragma unroll
                        for (int r = 0; r < 4; ++r)
                            Ps[(prow0 + r) * 68 + cb * 16 + l16] = f2bf(__expf(s[cb][r]));
                }
            }
            __syncthreads();

            bf16x8 bv[5][2];
            #pragma unroll
            for (int db = 0; db < 5; ++db) {
                const int vrow = db * 16 + l16;
                bv[db][0] = *(const bf16x8*)&Vs[vrow * 64 + pc0];
                bv[db][1] = *(const bf16x8*)&Vs[vrow * 64 + pc1];
            }
            #pragma unroll
            for (int sub = 0; sub < 2; ++sub) {
                if (kt > 2 * Q + sub) continue;
                const unsigned short* pb = &Ps[(sub * 64 + w * 16 + l16) * 68];
                bf16x8 ap0, ap1;
                *(bf16x4*)&ap0       = *(const bf16x4*)(pb + quad * 8);
                *((bf16x4*)&ap0 + 1) = *(const bf16x4*)(pb + quad * 8 + 4);
                *(bf16x4*)&ap1       = *(const bf16x4*)(pb + 32 + quad * 8);
                *((bf16x4*)&ap1 + 1) = *(const bf16x4*)(pb + 32 + quad * 8 + 4);
                #pragma unroll
                for (int db = 0; db < 5; ++db) {
                    o[sub][db] = __builtin_amdgcn_mfma_f32_16x16x32_bf16(ap0, bv[db][0], o[sub][db], 0, 0, 0);
                    o[sub][db] = __builtin_amdgcn_mfma_f32_16x16x32_bf16(ap1, bv[db][1], o[sub][db], 0, 0, 0);
                }
            }
            __syncthreads();
        }

        #pragma unroll
        for (int sub = 0; sub < 2; ++sub)
            #pragma unroll
            for (int r = 0; r < 4; ++r) {
                const float lsum = __shfl(o[sub][4][r], lane & 48);
                const float rinv = 1.0f / lsum;
                const int trow = qg0 + sub * 64 + w * 16 + quad * 4 + r;
                unsigned short* yp = y + (rowbase + trow) * (size_t)D_MODEL + h * 64 + l16;
                #pragma unroll
                for (int db = 0; db < 4; ++db)
                    yp[db * 16] = f2bf(o[sub][db][r] * rinv);
            }
    }
}

extern "C" void kernel_launch(void* const* d_in, const int* in_sizes, int n_in,
                              void* d_out, int out_size, void* d_ws, size_t ws_size,
                              hipStream_t stream) {
    (void)in_sizes; (void)n_in; (void)out_size; (void)ws_size;
    const float* x      = (const float*)d_in[0];
    const float* w_attn = (const float*)d_in[1];
    const float* w_o    = (const float*)d_in[2];
    const float* ln1_g  = (const float*)d_in[3];
    const float* ln1_b  = (const float*)d_in[4];
    const float* ln2_g  = (const float*)d_in[5];
    const float* ln2_b  = (const float*)d_in[6];
    const float* w_fc   = (const float*)d_in[7];
    const float* b_fc   = (const float*)d_in[8];
    const float* w_proj = (const float*)d_in[9];
    const float* b_proj = (const float*)d_in[10];
    float* out = (float*)d_out;

    char* ws = (char*)d_ws;
    unsigned short* ln_buf = (unsigned short*)ws;                           // 16 MiB @0
    unsigned short* qkbuf  = (unsigned short*)(ws + (size_t)16  * 1048576); // 32 MiB @16
    unsigned short* VTbuf  = (unsigned short*)(ws + (size_t)48  * 1048576); // 16 MiB @48
    unsigned short* hbuf   = (unsigned short*)(ws + (size_t)64  * 1048576); // 64 MiB @64
    unsigned short* wt_attn = hbuf;                                         // 6 MiB (hbuf dead until fc)
    unsigned short* wt_o    = hbuf + (size_t)3072 * 1024;                   // 2 MiB
    unsigned short* wt_fc   = qkbuf;                                        // 8 MiB (qkbuf dead after attn)
    unsigned short* wt_proj = qkbuf + (size_t)4096 * 1024;                  // 8 MiB
    unsigned short* pbuf    = (unsigned short*)(ws + (size_t)32 * 1048576); // 32 MiB (2x16, dead after attn)

    wt_kernel<<<dim3(3072 / 32, 1024 / 32), 256, 0, stream>>>(w_attn, wt_attn, 1024, 3072);
    wt_kernel<<<dim3(1024 / 32, 1024 / 32), 256, 0, stream>>>(w_o, wt_o, 1024, 1024);

    ln_kernel<<<NROWS, 256, 0, stream>>>(x, ln1_g, ln1_b, ln_buf);
    // QK projection (Q pre-scaled by 1/sqrt(hd))
    gemm_bt<false, true, true, false><<<dim3(2048 / 128, NROWS / 128), 256, 0, stream>>>(
        ln_buf, wt_attn, nullptr, nullptr, qkbuf, NROWS, 2048, 1024, 1024);
    // V^T projection
    gemm_bt<false, true, false, false><<<dim3(NROWS / 128, 1024 / 128), 256, 0, stream>>>(
        wt_attn + (size_t)2048 * 1024, ln_buf, nullptr, nullptr, VTbuf, 1024, NROWS, 1024, 1024);

    attn_kernel<<<dim3(8, BATCH * NHEAD), 256, 0, stream>>>(qkbuf, VTbuf, ln_buf);

    gemm_bt<false, false, false, false><<<dim3(1024 / 128, NROWS / 128), 256, 0, stream>>>(
        ln_buf, wt_o, nullptr, x, d_out, NROWS, 1024, 1024, 1024);

    ln_kernel<<<NROWS, 256, 0, stream>>>(out, ln2_g, ln2_b, ln_buf);

    wt_kernel<<<dim3(4096 / 32, 1024 / 32), 256, 0, stream>>>(w_fc, wt_fc, 1024, 4096);
    wt_kernel<<<dim3(1024 / 32, 4096 / 32), 256, 0, stream>>>(w_proj, wt_proj, 4096, 1024);

    // fc: 256x128 dense tile, gelu+bias fused
    gemm_big<<<dim3(4096 / 128, NROWS / 256), 256, 0, stream>>>(
        ln_buf, wt_fc, b_fc, hbuf, NROWS, 4096, 1024);

    // proj: split-K=2, bf16 partials (no atomics), then reduce into d_out
    gemm_bt<false, true, false, true><<<dim3(1024 / 128, NROWS / 128, 2), 256, 0, stream>>>(
        hbuf, wt_proj, nullptr, nullptr, pbuf, NROWS, 1024, 4096, 2048);
    reduce_kernel<<<NROWS, 256, 0, stream>>>(
        out, pbuf, pbuf + (size_t)NROWS * 1024, b_proj);
}

// Round 6
// 578.338 us; speedup vs baseline: 1.1210x; 1.0160x over previous
//
#include <hip/hip_runtime.h>
#include <math.h>

#define D_MODEL 1024
#define NHEAD   16
#define HDIM    64
#define SEQ     2048
#define BATCH   4
#define NROWS   (BATCH*SEQ)   // 8192

using bf16x8 = __attribute__((ext_vector_type(8))) short;
using bf16x4 = __attribute__((ext_vector_type(4))) short;
using f32x4  = __attribute__((ext_vector_type(4))) float;

__device__ __forceinline__ unsigned short f2bf(float f) {
    unsigned u = __float_as_uint(f);
    u += 0x7fffu + ((u >> 16) & 1u);
    return (unsigned short)(u >> 16);
}
__device__ __forceinline__ float bf2f(unsigned short h) {
    unsigned u = ((unsigned)h) << 16;
    return __uint_as_float(u);
}

#define ASYNC_COPY16(g, l) \
    __builtin_amdgcn_global_load_lds((__attribute__((address_space(1))) const void*)(g), \
                                     (__attribute__((address_space(3))) void*)(l), 16, 0, 0)

// ---------------- LayerNorm (LN1): one block per row of 1024 --------------------
__global__ __launch_bounds__(256) void ln_kernel(const float* __restrict__ x,
                                                 const float* __restrict__ g,
                                                 const float* __restrict__ b,
                                                 unsigned short* __restrict__ out) {
    const int row = blockIdx.x;
    const int tid = threadIdx.x;
    const float4* x4 = (const float4*)(x + (size_t)row * D_MODEL);
    float4 v = x4[tid];
    float s  = v.x + v.y + v.z + v.w;
    float sq = v.x*v.x + v.y*v.y + v.z*v.z + v.w*v.w;
    #pragma unroll
    for (int off = 32; off >= 1; off >>= 1) {
        s  += __shfl_down(s,  off, 64);
        sq += __shfl_down(sq, off, 64);
    }
    __shared__ float rs[4], rq[4];
    const int wave = tid >> 6;
    if ((tid & 63) == 0) { rs[wave] = s; rq[wave] = sq; }
    __syncthreads();
    const float tot  = rs[0] + rs[1] + rs[2] + rs[3];
    const float totq = rq[0] + rq[1] + rq[2] + rq[3];
    const float mu   = tot * (1.0f / D_MODEL);
    const float var  = totq * (1.0f / D_MODEL) - mu * mu;
    const float rstd = rsqrtf(var + 1e-5f);
    const float4 gv = ((const float4*)g)[tid];
    const float4 bv = ((const float4*)b)[tid];
    unsigned short* o = out + (size_t)row * D_MODEL + tid * 4;
    o[0] = f2bf((v.x - mu) * rstd * gv.x + bv.x);
    o[1] = f2bf((v.y - mu) * rstd * gv.y + bv.y);
    o[2] = f2bf((v.z - mu) * rstd * gv.z + bv.z);
    o[3] = f2bf((v.w - mu) * rstd * gv.w + bv.w);
}

// ------------- Weight transpose+convert: w[K][N] f32 -> wt[N][K] bf16 -----------
__global__ __launch_bounds__(256) void wt_kernel(const float* __restrict__ w,
                                                 unsigned short* __restrict__ wt,
                                                 int K, int N) {
    __shared__ float tile[32][33];
    const int n0 = blockIdx.x * 32, k0 = blockIdx.y * 32;
    const int tx = threadIdx.x & 31, ty = threadIdx.x >> 5;
    #pragma unroll
    for (int j = 0; j < 4; ++j)
        tile[ty + j * 8][tx] = w[(size_t)(k0 + ty + j * 8) * N + n0 + tx];
    __syncthreads();
    #pragma unroll
    for (int j = 0; j < 4; ++j)
        wt[(size_t)(n0 + ty + j * 8) * K + k0 + tx] = f2bf(tile[tx][ty + j * 8]);
}

// ------------- Merged QKV GEMM: ln[8192,1024] x wt_attn[3072,1024]^T ------------
// Q cols (<1024): x0.125 -> qk_out[row][col] (stride 2048)
// K cols (1024..2047):     -> qk_out[row][col]
// V cols (>=2048): transposed store -> vt_out[dv][tok]  (dv = col-2048)
__global__ __launch_bounds__(256) void gemm_qkv(const unsigned short* __restrict__ A,
                                                const unsigned short* __restrict__ Bt,
                                                unsigned short* __restrict__ qk_out,
                                                unsigned short* __restrict__ vt_out) {
    const int K = 1024;
    __shared__ __align__(16) unsigned short As[128 * 32];
    __shared__ __align__(16) unsigned short Bs[128 * 32];

    const int tid  = threadIdx.x;
    const int lane = tid & 63;
    const int wave = __builtin_amdgcn_readfirstlane(tid >> 6);
    const int quad = lane >> 4, l16 = lane & 15;
    const int wm = wave >> 1, wn = wave & 1;
    const int m0 = blockIdx.y * 128, n0 = blockIdx.x * 128;

    f32x4 acc[4][4] = {};

    const int rA = tid >> 2;
    const int p  = tid & 3;
    const int cs = (p ^ ((rA >> 1) & 3)) * 8;

    const unsigned short* Ag0 = A  + (size_t)(m0 + rA) * K + cs;
    const unsigned short* Ag1 = A  + (size_t)(m0 + rA + 64) * K + cs;
    const unsigned short* Bg0 = Bt + (size_t)(n0 + rA) * K + cs;
    const unsigned short* Bg1 = Bt + (size_t)(n0 + rA + 64) * K + cs;
    unsigned short* Al0 = As + tid * 8;
    unsigned short* Al1 = As + tid * 8 + 2048;
    unsigned short* Bl0 = Bs + tid * 8;
    unsigned short* Bl1 = Bs + tid * 8 + 2048;

    const int sw = (quad ^ ((l16 >> 1) & 3)) * 8;

    for (int kb = 0; kb < K; kb += 32) {
        ASYNC_COPY16(Ag0 + kb, Al0);
        ASYNC_COPY16(Ag1 + kb, Al1);
        ASYNC_COPY16(Bg0 + kb, Bl0);
        ASYNC_COPY16(Bg1 + kb, Bl1);
        __syncthreads();

        bf16x8 a[4], b[4];
        #pragma unroll
        for (int i = 0; i < 4; ++i)
            a[i] = *(const bf16x8*)&As[(wm * 64 + i * 16 + l16) * 32 + sw];
        #pragma unroll
        for (int j = 0; j < 4; ++j)
            b[j] = *(const bf16x8*)&Bs[(wn * 64 + j * 16 + l16) * 32 + sw];
        #pragma unroll
        for (int i = 0; i < 4; ++i)
            #pragma unroll
            for (int j = 0; j < 4; ++j)
                acc[i][j] = __builtin_amdgcn_mfma_f32_16x16x32_bf16(a[i], b[j], acc[i][j], 0, 0, 0);
        __syncthreads();
    }

    if (n0 < 2048) {
        const float sc = (n0 < 1024) ? 0.125f : 1.0f;   // block never straddles 1024
        #pragma unroll
        for (int i = 0; i < 4; ++i)
          #pragma unroll
          for (int j = 0; j < 4; ++j)
            #pragma unroll
            for (int r = 0; r < 4; ++r) {
                const int row = m0 + wm * 64 + i * 16 + quad * 4 + r;
                const int col = n0 + wn * 64 + j * 16 + l16;
                qk_out[(size_t)row * 2048 + col] = f2bf(acc[i][j][r] * sc);
            }
    } else {
        #pragma unroll
        for (int i = 0; i < 4; ++i)
          #pragma unroll
          for (int j = 0; j < 4; ++j) {
                const int dv  = n0 - 2048 + wn * 64 + j * 16 + l16;
                const int tok = m0 + wm * 64 + i * 16 + quad * 4;
                ushort4 pk;
                pk.x = f2bf(acc[i][j][0]); pk.y = f2bf(acc[i][j][1]);
                pk.z = f2bf(acc[i][j][2]); pk.w = f2bf(acc[i][j][3]);
                *(ushort4*)(vt_out + (size_t)dv * NROWS + tok) = pk;
            }
    }
}

// ------------- GEMM 128x128, BK=32: C = A[M,K] * Bt[N,K]^T ----------------------
// PARTIAL: split-K over blockIdx.z, bf16 partial to outp + z*M*N.
template<bool GELU, bool OUT_BF16, bool PARTIAL>
__global__ __launch_bounds__(256) void gemm_bt(const unsigned short* __restrict__ A,
                                               const unsigned short* __restrict__ Bt,
                                               const float* __restrict__ bias,
                                               const float* __restrict__ resid,
                                               void* __restrict__ outp,
                                               int M, int N, int K, int Kslice) {
    __shared__ __align__(16) unsigned short As[128 * 32];
    __shared__ __align__(16) unsigned short Bs[128 * 32];

    const int tid  = threadIdx.x;
    const int lane = tid & 63;
    const int wave = __builtin_amdgcn_readfirstlane(tid >> 6);
    const int quad = lane >> 4, l16 = lane & 15;
    const int wm = wave >> 1, wn = wave & 1;
    const int m0 = blockIdx.y * 128, n0 = blockIdx.x * 128;
    const int kbeg = PARTIAL ? blockIdx.z * Kslice : 0;

    f32x4 acc[4][4] = {};

    const int rA = tid >> 2;
    const int p  = tid & 3;
    const int cs = (p ^ ((rA >> 1) & 3)) * 8;

    const unsigned short* Ag0 = A  + (size_t)(m0 + rA) * K + cs + kbeg;
    const unsigned short* Ag1 = A  + (size_t)(m0 + rA + 64) * K + cs + kbeg;
    const unsigned short* Bg0 = Bt + (size_t)(n0 + rA) * K + cs + kbeg;
    const unsigned short* Bg1 = Bt + (size_t)(n0 + rA + 64) * K + cs + kbeg;
    unsigned short* Al0 = As + tid * 8;
    unsigned short* Al1 = As + tid * 8 + 2048;
    unsigned short* Bl0 = Bs + tid * 8;
    unsigned short* Bl1 = Bs + tid * 8 + 2048;

    const int sw = (quad ^ ((l16 >> 1) & 3)) * 8;

    for (int kb = 0; kb < Kslice; kb += 32) {
        ASYNC_COPY16(Ag0 + kb, Al0);
        ASYNC_COPY16(Ag1 + kb, Al1);
        ASYNC_COPY16(Bg0 + kb, Bl0);
        ASYNC_COPY16(Bg1 + kb, Bl1);
        __syncthreads();

        bf16x8 a[4], b[4];
        #pragma unroll
        for (int i = 0; i < 4; ++i)
            a[i] = *(const bf16x8*)&As[(wm * 64 + i * 16 + l16) * 32 + sw];
        #pragma unroll
        for (int j = 0; j < 4; ++j)
            b[j] = *(const bf16x8*)&Bs[(wn * 64 + j * 16 + l16) * 32 + sw];
        #pragma unroll
        for (int i = 0; i < 4; ++i)
            #pragma unroll
            for (int j = 0; j < 4; ++j)
                acc[i][j] = __builtin_amdgcn_mfma_f32_16x16x32_bf16(a[i], b[j], acc[i][j], 0, 0, 0);
        __syncthreads();
    }

    unsigned short* outb = (unsigned short*)outp;
    if (PARTIAL) outb += (size_t)blockIdx.z * M * N;

    #pragma unroll
    for (int i = 0; i < 4; ++i)
      #pragma unroll
      for (int j = 0; j < 4; ++j)
        #pragma unroll
        for (int r = 0; r < 4; ++r) {
            const int row = m0 + wm * 64 + i * 16 + quad * 4 + r;
            const int col = n0 + wn * 64 + j * 16 + l16;
            float v = acc[i][j][r];
            if (PARTIAL) {
                outb[(size_t)row * N + col] = f2bf(v);
            } else {
                if (bias) v += bias[col];
                if (GELU) {
                    const float u = 0.7978845608028654f * (v + 0.044715f * v * v * v);
                    const float e = __expf(2.0f * u);
                    v = 0.5f * v * (2.0f - 2.0f / (e + 1.0f));
                }
                if (resid) v += resid[(size_t)row * N + col];
                if (OUT_BF16) outb[(size_t)row * N + col] = f2bf(v);
                else          ((float*)outp)[(size_t)row * N + col] = v;
            }
        }
}

// ------------- GEMM 256x128, BK=32: dense-MFMA tile for fc (bias+gelu) ----------
__global__ __launch_bounds__(256, 2) void gemm_big(const unsigned short* __restrict__ A,
                                                   const unsigned short* __restrict__ Bt,
                                                   const float* __restrict__ bias,
                                                   unsigned short* __restrict__ outb,
                                                   int M, int N, int K) {
    __shared__ __align__(16) unsigned short As[256 * 32];
    __shared__ __align__(16) unsigned short Bs[128 * 32];

    const int tid  = threadIdx.x;
    const int lane = tid & 63;
    const int wave = __builtin_amdgcn_readfirstlane(tid >> 6);
    const int quad = lane >> 4, l16 = lane & 15;
    const int wm = wave >> 1, wn = wave & 1;
    const int m0 = blockIdx.y * 256, n0 = blockIdx.x * 128;

    f32x4 acc[8][4] = {};

    const int rr = tid >> 2;
    const int p  = tid & 3;
    const int cs = (p ^ ((rr >> 1) & 3)) * 8;

    const unsigned short* Ag[4];
    const unsigned short* Bg[2];
    #pragma unroll
    for (int i = 0; i < 4; ++i)
        Ag[i] = A + (size_t)(m0 + i * 64 + rr) * K + cs;
    #pragma unroll
    for (int i = 0; i < 2; ++i)
        Bg[i] = Bt + (size_t)(n0 + i * 64 + rr) * K + cs;

    const int sw = (quad ^ ((l16 >> 1) & 3)) * 8;

    for (int kb = 0; kb < K; kb += 32) {
        #pragma unroll
        for (int i = 0; i < 4; ++i)
            ASYNC_COPY16(Ag[i] + kb, As + i * 2048 + tid * 8);
        #pragma unroll
        for (int i = 0; i < 2; ++i)
            ASYNC_COPY16(Bg[i] + kb, Bs + i * 2048 + tid * 8);
        __syncthreads();

        bf16x8 b[4];
        #pragma unroll
        for (int j = 0; j < 4; ++j)
            b[j] = *(const bf16x8*)&Bs[(wn * 64 + j * 16 + l16) * 32 + sw];
        #pragma unroll
        for (int i = 0; i < 8; ++i) {
            bf16x8 a = *(const bf16x8*)&As[(wm * 128 + i * 16 + l16) * 32 + sw];
            #pragma unroll
            for (int j = 0; j < 4; ++j)
                acc[i][j] = __builtin_amdgcn_mfma_f32_16x16x32_bf16(a, b[j], acc[i][j], 0, 0, 0);
        }
        __syncthreads();
    }

    #pragma unroll
    for (int i = 0; i < 8; ++i)
      #pragma unroll
      for (int j = 0; j < 4; ++j)
        #pragma unroll
        for (int r = 0; r < 4; ++r) {
            const int row = m0 + wm * 128 + i * 16 + quad * 4 + r;
            const int col = n0 + wn * 64 + j * 16 + l16;
            float v = acc[i][j][r] + bias[col];
            const float u = 0.7978845608028654f * (v + 0.044715f * v * v * v);
            const float e = __expf(2.0f * u);
            v = 0.5f * v * (2.0f - 2.0f / (e + 1.0f));
            outb[(size_t)row * N + col] = f2bf(v);
        }
}

// ------- fused w_o reduce: res1 = x + p0..p3 -> d_out(f32); LN2(res1) -> lnout --
__global__ __launch_bounds__(256) void reduce_wo_ln2(const float* __restrict__ x,
                                                     const unsigned short* __restrict__ pw,
                                                     const float* __restrict__ g,
                                                     const float* __restrict__ bb,
                                                     float* __restrict__ out,
                                                     unsigned short* __restrict__ lnout) {
    const int row = blockIdx.x;
    const int tid = threadIdx.x;
    const size_t base = (size_t)row * D_MODEL + tid * 4;
    const size_t stride = (size_t)NROWS * D_MODEL;
    float4 v = *(const float4*)(x + base);
    #pragma unroll
    for (int z = 0; z < 4; ++z) {
        ushort4 a = *(const ushort4*)(pw + z * stride + base);
        v.x += bf2f(a.x); v.y += bf2f(a.y); v.z += bf2f(a.z); v.w += bf2f(a.w);
    }
    *(float4*)(out + base) = v;

    float s  = v.x + v.y + v.z + v.w;
    float sq = v.x*v.x + v.y*v.y + v.z*v.z + v.w*v.w;
    #pragma unroll
    for (int off = 32; off >= 1; off >>= 1) {
        s  += __shfl_down(s,  off, 64);
        sq += __shfl_down(sq, off, 64);
    }
    __shared__ float rs[4], rq[4];
    const int wave = tid >> 6;
    if ((tid & 63) == 0) { rs[wave] = s; rq[wave] = sq; }
    __syncthreads();
    const float tot  = rs[0] + rs[1] + rs[2] + rs[3];
    const float totq = rq[0] + rq[1] + rq[2] + rq[3];
    const float mu   = tot * (1.0f / D_MODEL);
    const float var  = totq * (1.0f / D_MODEL) - mu * mu;
    const float rstd = rsqrtf(var + 1e-5f);
    const float4 gv = ((const float4*)g)[tid];
    const float4 bv = ((const float4*)bb)[tid];
    unsigned short* o = lnout + (size_t)row * D_MODEL + tid * 4;
    o[0] = f2bf((v.x - mu) * rstd * gv.x + bv.x);
    o[1] = f2bf((v.y - mu) * rstd * gv.y + bv.y);
    o[2] = f2bf((v.z - mu) * rstd * gv.z + bv.z);
    o[3] = f2bf((v.w - mu) * rstd * gv.w + bv.w);
}

// ------------- proj split-K reduce: out += bias + p0 + p1 -----------------------
__global__ __launch_bounds__(256) void reduce_kernel(float* __restrict__ out,
                                                     const unsigned short* __restrict__ p0,
                                                     const unsigned short* __restrict__ p1,
                                                     const float* __restrict__ bias) {
    const int row = blockIdx.x;
    const int c0 = threadIdx.x * 4;
    const size_t base = (size_t)row * D_MODEL + c0;
    float4 o = *(float4*)(out + base);
    ushort4 a = *(const ushort4*)(p0 + base);
    ushort4 b = *(const ushort4*)(p1 + base);
    const float4 bs = *(const float4*)(bias + c0);
    o.x += bs.x + bf2f(a.x) + bf2f(b.x);
    o.y += bs.y + bf2f(a.y) + bf2f(b.y);
    o.z += bs.z + bf2f(a.z) + bf2f(b.z);
    o.w += bs.w + bf2f(a.w) + bf2f(b.w);
    *(float4*)(out + base) = o;
}

// ---------------- Flash attention, causal, balanced (paired 128-q tiles) --------
__global__ __launch_bounds__(256) void attn_kernel(const unsigned short* __restrict__ qk,
                                                   const unsigned short* __restrict__ VT,
                                                   unsigned short* __restrict__ y) {
    __shared__ __align__(16) unsigned short Qs[128 * 64];
    __shared__ __align__(16) unsigned short Ks[64 * 64];
    __shared__ __align__(16) unsigned short Vs[80 * 64];
    __shared__ __align__(16) unsigned short Ps[128 * 68];

    const int tid  = threadIdx.x;
    const int lane = tid & 63, w = tid >> 6;
    const int quad = lane >> 4, l16 = lane & 15;
    const int s7   = l16 & 7;
    const int pc0  = (quad ^ s7) * 8;
    const int pc1  = ((quad + 4) ^ s7) * 8;
    const int srow = tid >> 3, sp = tid & 7;

    const int pairidx = blockIdx.x;
    const int bh = blockIdx.y;
    const int b = bh >> 4, h = bh & 15;
    const size_t rowbase = (size_t)b * SEQ;
    const unsigned short* Qbase = qk + h * 64;
    const unsigned short* Kbase = qk + 1024 + h * 64;
    const unsigned short* Vbase = VT + (size_t)(h * 64) * NROWS + b * SEQ;

    #pragma unroll
    for (int e = 0; e < 4; ++e) {
        const int off = tid * 4 + e;
        Vs[4096 + off] = (off < 64) ? (unsigned short)0x3F80 : (unsigned short)0;
    }

    for (int phase = 0; phase < 2; ++phase) {
        const int Q = phase ? pairidx : (15 - pairidx);
        const int nkt = 2 * Q + 2;
        const int qg0 = Q * 128;

        #pragma unroll
        for (int i = 0; i < 4; ++i) {
            const int row = i * 32 + srow;
            const int c = sp ^ (row & 7);
            ASYNC_COPY16(Qbase + (rowbase + qg0 + row) * 2048 + c * 8,
                         (char*)Qs + i * 4096 + tid * 16);
        }
        __syncthreads();

        bf16x8 aq[2][2];
        #pragma unroll
        for (int sub = 0; sub < 2; ++sub) {
            const int qrow = sub * 64 + w * 16 + l16;
            aq[sub][0] = *(const bf16x8*)&Qs[qrow * 64 + pc0];
            aq[sub][1] = *(const bf16x8*)&Qs[qrow * 64 + pc1];
        }

        f32x4 o[2][5] = {};

        for (int kt = 0; kt < nkt; ++kt) {
            #pragma unroll
            for (int i = 0; i < 2; ++i) {
                const int row = i * 32 + srow;
                const int c = sp ^ (row & 7);
                ASYNC_COPY16(Kbase + (rowbase + kt * 64 + row) * 2048 + c * 8,
                             (char*)Ks + i * 4096 + tid * 16);
                ASYNC_COPY16(Vbase + (size_t)row * NROWS + kt * 64 + c * 8,
                             (char*)Vs + i * 4096 + tid * 16);
            }
            __syncthreads();

            bf16x8 bk[4][2];
            #pragma unroll
            for (int cb = 0; cb < 4; ++cb) {
                const int krow = cb * 16 + l16;
                bk[cb][0] = *(const bf16x8*)&Ks[krow * 64 + pc0];
                bk[cb][1] = *(const bf16x8*)&Ks[krow * 64 + pc1];
            }

            #pragma unroll
            for (int sub = 0; sub < 2; ++sub) {
                if (kt > 2 * Q + sub) continue;
                f32x4 s[4] = {};
                #pragma unroll
                for (int cb = 0; cb < 4; ++cb) {
                    s[cb] = __builtin_amdgcn_mfma_f32_16x16x32_bf16(aq[sub][0], bk[cb][0], s[cb], 0, 0, 0);
                    s[cb] = __builtin_amdgcn_mfma_f32_16x16x32_bf16(aq[sub][1], bk[cb][1], s[cb], 0, 0, 0);
                }
                const int prow0 = sub * 64 + w * 16 + quad * 4;
                if (kt == 2 * Q + sub) {
                    const int qg = qg0 + prow0;
                    const int kg = kt * 64 + l16;
                    #pragma unroll
                    for (int cb = 0; cb < 4; ++cb)
                        #pragma unroll
                        for (int r = 0; r < 4; ++r) {
                            const float e = __expf(s[cb][r]);
                            const float pv = (kg + cb * 16 > qg + r) ? 0.0f : e;
                            Ps[(prow0 + r) * 68 + cb * 16 + l16] = f2bf(pv);
                        }
                } else {
                    #pragma unroll
                    for (int cb = 0; cb < 4; ++cb)
                        #pragma unroll
                        for (int r = 0; r < 4; ++r)
                            Ps[(prow0 + r) * 68 + cb * 16 + l16] = f2bf(__expf(s[cb][r]));
                }
            }
            __syncthreads();

            bf16x8 bv[5][2];
            #pragma unroll
            for (int db = 0; db < 5; ++db) {
                const int vrow = db * 16 + l16;
                bv[db][0] = *(const bf16x8*)&Vs[vrow * 64 + pc0];
                bv[db][1] = *(const bf16x8*)&Vs[vrow * 64 + pc1];
            }
            #pragma unroll
            for (int sub = 0; sub < 2; ++sub) {
                if (kt > 2 * Q + sub) continue;
                const unsigned short* pb = &Ps[(sub * 64 + w * 16 + l16) * 68];
                bf16x8 ap0, ap1;
                *(bf16x4*)&ap0       = *(const bf16x4*)(pb + quad * 8);
                *((bf16x4*)&ap0 + 1) = *(const bf16x4*)(pb + quad * 8 + 4);
                *(bf16x4*)&ap1       = *(const bf16x4*)(pb + 32 + quad * 8);
                *((bf16x4*)&ap1 + 1) = *(const bf16x4*)(pb + 32 + quad * 8 + 4);
                #pragma unroll
                for (int db = 0; db < 5; ++db) {
                    o[sub][db] = __builtin_amdgcn_mfma_f32_16x16x32_bf16(ap0, bv[db][0], o[sub][db], 0, 0, 0);
                    o[sub][db] = __builtin_amdgcn_mfma_f32_16x16x32_bf16(ap1, bv[db][1], o[sub][db], 0, 0, 0);
                }
            }
            __syncthreads();
        }

        #pragma unroll
        for (int sub = 0; sub < 2; ++sub)
            #pragma unroll
            for (int r = 0; r < 4; ++r) {
                const float lsum = __shfl(o[sub][4][r], lane & 48);
                const float rinv = 1.0f / lsum;
                const int trow = qg0 + sub * 64 + w * 16 + quad * 4 + r;
                unsigned short* yp = y + (rowbase + trow) * (size_t)D_MODEL + h * 64 + l16;
                #pragma unroll
                for (int db = 0; db < 4; ++db)
                    yp[db * 16] = f2bf(o[sub][db][r] * rinv);
            }
    }
}

extern "C" void kernel_launch(void* const* d_in, const int* in_sizes, int n_in,
                              void* d_out, int out_size, void* d_ws, size_t ws_size,
                              hipStream_t stream) {
    (void)in_sizes; (void)n_in; (void)out_size; (void)ws_size;
    const float* x      = (const float*)d_in[0];
    const float* w_attn = (const float*)d_in[1];
    const float* w_o    = (const float*)d_in[2];
    const float* ln1_g  = (const float*)d_in[3];
    const float* ln1_b  = (const float*)d_in[4];
    const float* ln2_g  = (const float*)d_in[5];
    const float* ln2_b  = (const float*)d_in[6];
    const float* w_fc   = (const float*)d_in[7];
    const float* b_fc   = (const float*)d_in[8];
    const float* w_proj = (const float*)d_in[9];
    const float* b_proj = (const float*)d_in[10];
    float* out = (float*)d_out;

    char* ws = (char*)d_ws;
    const size_t MiB = 1048576;
    // Memory map (MiB):  0..16 ln_buf | 16..48 qkbuf -> pw(16..80) -> wt_fc/proj(16..32)+pp(32..64)
    //                    48..64 VTbuf | 64..70 wt_attn | 64..128 hbuf (fc out) | 126..128 wt_o
    unsigned short* ln_buf  = (unsigned short*)ws;
    unsigned short* qkbuf   = (unsigned short*)(ws + 16 * MiB);
    unsigned short* VTbuf   = (unsigned short*)(ws + 48 * MiB);
    unsigned short* wt_attn = (unsigned short*)(ws + 64 * MiB);
    unsigned short* hbuf    = (unsigned short*)(ws + 64 * MiB);
    unsigned short* wt_o    = (unsigned short*)(ws + 126 * MiB);
    unsigned short* pw      = (unsigned short*)(ws + 16 * MiB);   // 4 x 16 MiB (after attn)
    unsigned short* wt_fc   = (unsigned short*)(ws + 16 * MiB);   // after reduce_wo
    unsigned short* wt_proj = (unsigned short*)(ws + 24 * MiB);
    unsigned short* pp      = (unsigned short*)(ws + 32 * MiB);   // 2 x 16 MiB

    wt_kernel<<<dim3(3072 / 32, 1024 / 32), 256, 0, stream>>>(w_attn, wt_attn, 1024, 3072);
    wt_kernel<<<dim3(1024 / 32, 1024 / 32), 256, 0, stream>>>(w_o, wt_o, 1024, 1024);

    ln_kernel<<<NROWS, 256, 0, stream>>>(x, ln1_g, ln1_b, ln_buf);

    // merged QKV: Q(scaled)/K -> qkbuf [8192][2048], V -> VTbuf [1024][8192] (transposed)
    gemm_qkv<<<dim3(3072 / 128, NROWS / 128), 256, 0, stream>>>(
        ln_buf, wt_attn, qkbuf, VTbuf);

    attn_kernel<<<dim3(8, BATCH * NHEAD), 256, 0, stream>>>(qkbuf, VTbuf, ln_buf);

    // w_o: split-K=4 partials (qkbuf/VT/wt_attn regions now dead)
    gemm_bt<false, true, true><<<dim3(1024 / 128, NROWS / 128, 4), 256, 0, stream>>>(
        ln_buf, wt_o, nullptr, nullptr, pw, NROWS, 1024, 1024, 256);
    // res1 = x + sum(pw) -> d_out ; LN2(res1) -> ln_buf
    reduce_wo_ln2<<<NROWS, 256, 0, stream>>>(x, pw, ln2_g, ln2_b, out, ln_buf);

    wt_kernel<<<dim3(4096 / 32, 1024 / 32), 256, 0, stream>>>(w_fc, wt_fc, 1024, 4096);
    wt_kernel<<<dim3(1024 / 32, 4096 / 32), 256, 0, stream>>>(w_proj, wt_proj, 4096, 1024);

    // fc: 256x128 dense tile, gelu+bias fused
    gemm_big<<<dim3(4096 / 128, NROWS / 256), 256, 0, stream>>>(
        ln_buf, wt_fc, b_fc, hbuf, NROWS, 4096, 1024);

    // proj: split-K=2 partials, then reduce into d_out
    gemm_bt<false, true, true><<<dim3(1024 / 128, NROWS / 128, 2), 256, 0, stream>>>(
        hbuf, wt_proj, nullptr, nullptr, pp, NROWS, 1024, 4096, 2048);
    reduce_kernel<<<NROWS, 256, 0, stream>>>(
        out, pp, pp + (size_t)NROWS * 1024, b_proj);
}

// Round 7
// 546.311 us; speedup vs baseline: 1.1867x; 1.0586x over previous
//
#include <hip/hip_runtime.h>
#include <math.h>

#define D_MODEL 1024
#define NHEAD   16
#define HDIM    64
#define SEQ     2048
#define BATCH   4
#define NROWS   (BATCH*SEQ)   // 8192

using bf16x8 = __attribute__((ext_vector_type(8))) short;
using bf16x4 = __attribute__((ext_vector_type(4))) short;
using f32x4  = __attribute__((ext_vector_type(4))) float;

__device__ __forceinline__ unsigned short f2bf(float f) {
    unsigned u = __float_as_uint(f);
    u += 0x7fffu + ((u >> 16) & 1u);
    return (unsigned short)(u >> 16);
}
__device__ __forceinline__ float bf2f(unsigned short h) {
    unsigned u = ((unsigned)h) << 16;
    return __uint_as_float(u);
}

#define ASYNC_COPY16(g, l) \
    __builtin_amdgcn_global_load_lds((__attribute__((address_space(1))) const void*)(g), \
                                     (__attribute__((address_space(3))) void*)(l), 16, 0, 0)

// ---------------- LayerNorm (LN1): one block per row of 1024 --------------------
__global__ __launch_bounds__(256) void ln_kernel(const float* __restrict__ x,
                                                 const float* __restrict__ g,
                                                 const float* __restrict__ b,
                                                 unsigned short* __restrict__ out) {
    const int row = blockIdx.x;
    const int tid = threadIdx.x;
    const float4* x4 = (const float4*)(x + (size_t)row * D_MODEL);
    float4 v = x4[tid];
    float s  = v.x + v.y + v.z + v.w;
    float sq = v.x*v.x + v.y*v.y + v.z*v.z + v.w*v.w;
    #pragma unroll
    for (int off = 32; off >= 1; off >>= 1) {
        s  += __shfl_down(s,  off, 64);
        sq += __shfl_down(sq, off, 64);
    }
    __shared__ float rs[4], rq[4];
    const int wave = tid >> 6;
    if ((tid & 63) == 0) { rs[wave] = s; rq[wave] = sq; }
    __syncthreads();
    const float tot  = rs[0] + rs[1] + rs[2] + rs[3];
    const float totq = rq[0] + rq[1] + rq[2] + rq[3];
    const float mu   = tot * (1.0f / D_MODEL);
    const float var  = totq * (1.0f / D_MODEL) - mu * mu;
    const float rstd = rsqrtf(var + 1e-5f);
    const float4 gv = ((const float4*)g)[tid];
    const float4 bv = ((const float4*)b)[tid];
    unsigned short* o = out + (size_t)row * D_MODEL + tid * 4;
    o[0] = f2bf((v.x - mu) * rstd * gv.x + bv.x);
    o[1] = f2bf((v.y - mu) * rstd * gv.y + bv.y);
    o[2] = f2bf((v.z - mu) * rstd * gv.z + bv.z);
    o[3] = f2bf((v.w - mu) * rstd * gv.w + bv.w);
}

// ------------- Weight transpose+convert: w[K][N] f32 -> wt[N][K] bf16 -----------
__global__ __launch_bounds__(256) void wt_kernel(const float* __restrict__ w,
                                                 unsigned short* __restrict__ wt,
                                                 int K, int N) {
    __shared__ float tile[32][33];
    const int n0 = blockIdx.x * 32, k0 = blockIdx.y * 32;
    const int tx = threadIdx.x & 31, ty = threadIdx.x >> 5;
    #pragma unroll
    for (int j = 0; j < 4; ++j)
        tile[ty + j * 8][tx] = w[(size_t)(k0 + ty + j * 8) * N + n0 + tx];
    __syncthreads();
    #pragma unroll
    for (int j = 0; j < 4; ++j)
        wt[(size_t)(n0 + ty + j * 8) * K + k0 + tx] = f2bf(tile[tx][ty + j * 8]);
}

// ------------- Merged QKV GEMM (grid: x = m-block, y = n-block) -----------------
__global__ __launch_bounds__(256) void gemm_qkv(const unsigned short* __restrict__ A,
                                                const unsigned short* __restrict__ Bt,
                                                unsigned short* __restrict__ qk_out,
                                                unsigned short* __restrict__ vt_out) {
    const int K = 1024;
    __shared__ __align__(16) unsigned short As[128 * 32];
    __shared__ __align__(16) unsigned short Bs[128 * 32];

    const int tid  = threadIdx.x;
    const int lane = tid & 63;
    const int wave = __builtin_amdgcn_readfirstlane(tid >> 6);
    const int quad = lane >> 4, l16 = lane & 15;
    const int wm = wave >> 1, wn = wave & 1;
    const int m0 = blockIdx.x * 128, n0 = blockIdx.y * 128;

    f32x4 acc[4][4] = {};

    const int rA = tid >> 2;
    const int p  = tid & 3;
    const int cs = (p ^ ((rA >> 1) & 3)) * 8;

    const unsigned short* Ag0 = A  + (size_t)(m0 + rA) * K + cs;
    const unsigned short* Ag1 = A  + (size_t)(m0 + rA + 64) * K + cs;
    const unsigned short* Bg0 = Bt + (size_t)(n0 + rA) * K + cs;
    const unsigned short* Bg1 = Bt + (size_t)(n0 + rA + 64) * K + cs;
    unsigned short* Al0 = As + tid * 8;
    unsigned short* Al1 = As + tid * 8 + 2048;
    unsigned short* Bl0 = Bs + tid * 8;
    unsigned short* Bl1 = Bs + tid * 8 + 2048;

    const int sw = (quad ^ ((l16 >> 1) & 3)) * 8;

    for (int kb = 0; kb < K; kb += 32) {
        ASYNC_COPY16(Ag0 + kb, Al0);
        ASYNC_COPY16(Ag1 + kb, Al1);
        ASYNC_COPY16(Bg0 + kb, Bl0);
        ASYNC_COPY16(Bg1 + kb, Bl1);
        __syncthreads();

        bf16x8 a[4], b[4];
        #pragma unroll
        for (int i = 0; i < 4; ++i)
            a[i] = *(const bf16x8*)&As[(wm * 64 + i * 16 + l16) * 32 + sw];
        #pragma unroll
        for (int j = 0; j < 4; ++j)
            b[j] = *(const bf16x8*)&Bs[(wn * 64 + j * 16 + l16) * 32 + sw];
        #pragma unroll
        for (int i = 0; i < 4; ++i)
            #pragma unroll
            for (int j = 0; j < 4; ++j)
                acc[i][j] = __builtin_amdgcn_mfma_f32_16x16x32_bf16(a[i], b[j], acc[i][j], 0, 0, 0);
        __syncthreads();
    }

    if (n0 < 2048) {
        const float sc = (n0 < 1024) ? 0.125f : 1.0f;   // block never straddles 1024
        #pragma unroll
        for (int i = 0; i < 4; ++i)
          #pragma unroll
          for (int j = 0; j < 4; ++j)
            #pragma unroll
            for (int r = 0; r < 4; ++r) {
                const int row = m0 + wm * 64 + i * 16 + quad * 4 + r;
                const int col = n0 + wn * 64 + j * 16 + l16;
                qk_out[(size_t)row * 2048 + col] = f2bf(acc[i][j][r] * sc);
            }
    } else {
        #pragma unroll
        for (int i = 0; i < 4; ++i)
          #pragma unroll
          for (int j = 0; j < 4; ++j) {
                const int dv  = n0 - 2048 + wn * 64 + j * 16 + l16;
                const int tok = m0 + wm * 64 + i * 16 + quad * 4;
                ushort4 pk;
                pk.x = f2bf(acc[i][j][0]); pk.y = f2bf(acc[i][j][1]);
                pk.z = f2bf(acc[i][j][2]); pk.w = f2bf(acc[i][j][3]);
                *(ushort4*)(vt_out + (size_t)dv * NROWS + tok) = pk;
            }
    }
}

// ------------- GEMM 128x128, BK=32 (grid: x = m-block, y = n-block) -------------
// PARTIAL: split-K over blockIdx.z (slice z covers [z*Kslice, ...); last slice
// extends to K), bf16 partial to outp + z*M*N.
template<bool GELU, bool OUT_BF16, bool PARTIAL>
__global__ __launch_bounds__(256) void gemm_bt(const unsigned short* __restrict__ A,
                                               const unsigned short* __restrict__ Bt,
                                               const float* __restrict__ bias,
                                               const float* __restrict__ resid,
                                               void* __restrict__ outp,
                                               int M, int N, int K, int Kslice) {
    __shared__ __align__(16) unsigned short As[128 * 32];
    __shared__ __align__(16) unsigned short Bs[128 * 32];

    const int tid  = threadIdx.x;
    const int lane = tid & 63;
    const int wave = __builtin_amdgcn_readfirstlane(tid >> 6);
    const int quad = lane >> 4, l16 = lane & 15;
    const int wm = wave >> 1, wn = wave & 1;
    const int m0 = blockIdx.x * 128, n0 = blockIdx.y * 128;
    const int kbeg = PARTIAL ? blockIdx.z * Kslice : 0;
    const int klen = PARTIAL ? ((blockIdx.z == gridDim.z - 1) ? (K - kbeg) : Kslice)
                             : K;

    f32x4 acc[4][4] = {};

    const int rA = tid >> 2;
    const int p  = tid & 3;
    const int cs = (p ^ ((rA >> 1) & 3)) * 8;

    const unsigned short* Ag0 = A  + (size_t)(m0 + rA) * K + cs + kbeg;
    const unsigned short* Ag1 = A  + (size_t)(m0 + rA + 64) * K + cs + kbeg;
    const unsigned short* Bg0 = Bt + (size_t)(n0 + rA) * K + cs + kbeg;
    const unsigned short* Bg1 = Bt + (size_t)(n0 + rA + 64) * K + cs + kbeg;
    unsigned short* Al0 = As + tid * 8;
    unsigned short* Al1 = As + tid * 8 + 2048;
    unsigned short* Bl0 = Bs + tid * 8;
    unsigned short* Bl1 = Bs + tid * 8 + 2048;

    const int sw = (quad ^ ((l16 >> 1) & 3)) * 8;

    for (int kb = 0; kb < klen; kb += 32) {
        ASYNC_COPY16(Ag0 + kb, Al0);
        ASYNC_COPY16(Ag1 + kb, Al1);
        ASYNC_COPY16(Bg0 + kb, Bl0);
        ASYNC_COPY16(Bg1 + kb, Bl1);
        __syncthreads();

        bf16x8 a[4], b[4];
        #pragma unroll
        for (int i = 0; i < 4; ++i)
            a[i] = *(const bf16x8*)&As[(wm * 64 + i * 16 + l16) * 32 + sw];
        #pragma unroll
        for (int j = 0; j < 4; ++j)
            b[j] = *(const bf16x8*)&Bs[(wn * 64 + j * 16 + l16) * 32 + sw];
        #pragma unroll
        for (int i = 0; i < 4; ++i)
            #pragma unroll
            for (int j = 0; j < 4; ++j)
                acc[i][j] = __builtin_amdgcn_mfma_f32_16x16x32_bf16(a[i], b[j], acc[i][j], 0, 0, 0);
        __syncthreads();
    }

    unsigned short* outb = (unsigned short*)outp;
    if (PARTIAL) outb += (size_t)blockIdx.z * M * N;

    #pragma unroll
    for (int i = 0; i < 4; ++i)
      #pragma unroll
      for (int j = 0; j < 4; ++j)
        #pragma unroll
        for (int r = 0; r < 4; ++r) {
            const int row = m0 + wm * 64 + i * 16 + quad * 4 + r;
            const int col = n0 + wn * 64 + j * 16 + l16;
            float v = acc[i][j][r];
            if (PARTIAL) {
                outb[(size_t)row * N + col] = f2bf(v);
            } else {
                if (bias) v += bias[col];
                if (GELU) {
                    const float u = 0.7978845608028654f * (v + 0.044715f * v * v * v);
                    const float e = __expf(2.0f * u);
                    v = 0.5f * v * (2.0f - 2.0f / (e + 1.0f));
                }
                if (resid) v += resid[(size_t)row * N + col];
                if (OUT_BF16) outb[(size_t)row * N + col] = f2bf(v);
                else          ((float*)outp)[(size_t)row * N + col] = v;
            }
        }
}

// ------------- GEMM 256x128 (grid: x = m-block, y = n-block): fc ----------------
__global__ __launch_bounds__(256, 2) void gemm_big(const unsigned short* __restrict__ A,
                                                   const unsigned short* __restrict__ Bt,
                                                   const float* __restrict__ bias,
                                                   unsigned short* __restrict__ outb,
                                                   int M, int N, int K) {
    __shared__ __align__(16) unsigned short As[256 * 32];
    __shared__ __align__(16) unsigned short Bs[128 * 32];

    const int tid  = threadIdx.x;
    const int lane = tid & 63;
    const int wave = __builtin_amdgcn_readfirstlane(tid >> 6);
    const int quad = lane >> 4, l16 = lane & 15;
    const int wm = wave >> 1, wn = wave & 1;
    const int m0 = blockIdx.x * 256, n0 = blockIdx.y * 128;

    f32x4 acc[8][4] = {};

    const int rr = tid >> 2;
    const int p  = tid & 3;
    const int cs = (p ^ ((rr >> 1) & 3)) * 8;

    const unsigned short* Ag[4];
    const unsigned short* Bg[2];
    #pragma unroll
    for (int i = 0; i < 4; ++i)
        Ag[i] = A + (size_t)(m0 + i * 64 + rr) * K + cs;
    #pragma unroll
    for (int i = 0; i < 2; ++i)
        Bg[i] = Bt + (size_t)(n0 + i * 64 + rr) * K + cs;

    const int sw = (quad ^ ((l16 >> 1) & 3)) * 8;

    for (int kb = 0; kb < K; kb += 32) {
        #pragma unroll
        for (int i = 0; i < 4; ++i)
            ASYNC_COPY16(Ag[i] + kb, As + i * 2048 + tid * 8);
        #pragma unroll
        for (int i = 0; i < 2; ++i)
            ASYNC_COPY16(Bg[i] + kb, Bs + i * 2048 + tid * 8);
        __syncthreads();

        bf16x8 b[4];
        #pragma unroll
        for (int j = 0; j < 4; ++j)
            b[j] = *(const bf16x8*)&Bs[(wn * 64 + j * 16 + l16) * 32 + sw];
        #pragma unroll
        for (int i = 0; i < 8; ++i) {
            bf16x8 a = *(const bf16x8*)&As[(wm * 128 + i * 16 + l16) * 32 + sw];
            #pragma unroll
            for (int j = 0; j < 4; ++j)
                acc[i][j] = __builtin_amdgcn_mfma_f32_16x16x32_bf16(a, b[j], acc[i][j], 0, 0, 0);
        }
        __syncthreads();
    }

    #pragma unroll
    for (int i = 0; i < 8; ++i)
      #pragma unroll
      for (int j = 0; j < 4; ++j)
        #pragma unroll
        for (int r = 0; r < 4; ++r) {
            const int row = m0 + wm * 128 + i * 16 + quad * 4 + r;
            const int col = n0 + wn * 64 + j * 16 + l16;
            float v = acc[i][j][r] + bias[col];
            const float u = 0.7978845608028654f * (v + 0.044715f * v * v * v);
            const float e = __expf(2.0f * u);
            v = 0.5f * v * (2.0f - 2.0f / (e + 1.0f));
            outb[(size_t)row * N + col] = f2bf(v);
        }
}

// ------- fused w_o reduce: res1 = x + p0..p3 -> d_out(f32); LN2(res1) -> lnout --
__global__ __launch_bounds__(256) void reduce_wo_ln2(const float* __restrict__ x,
                                                     const unsigned short* __restrict__ pw,
                                                     const float* __restrict__ g,
                                                     const float* __restrict__ bb,
                                                     float* __restrict__ out,
                                                     unsigned short* __restrict__ lnout) {
    const int row = blockIdx.x;
    const int tid = threadIdx.x;
    const size_t base = (size_t)row * D_MODEL + tid * 4;
    const size_t stride = (size_t)NROWS * D_MODEL;
    float4 v = *(const float4*)(x + base);
    #pragma unroll
    for (int z = 0; z < 4; ++z) {
        ushort4 a = *(const ushort4*)(pw + z * stride + base);
        v.x += bf2f(a.x); v.y += bf2f(a.y); v.z += bf2f(a.z); v.w += bf2f(a.w);
    }
    *(float4*)(out + base) = v;

    float s  = v.x + v.y + v.z + v.w;
    float sq = v.x*v.x + v.y*v.y + v.z*v.z + v.w*v.w;
    #pragma unroll
    for (int off = 32; off >= 1; off >>= 1) {
        s  += __shfl_down(s,  off, 64);
        sq += __shfl_down(sq, off, 64);
    }
    __shared__ float rs[4], rq[4];
    const int wave = tid >> 6;
    if ((tid & 63) == 0) { rs[wave] = s; rq[wave] = sq; }
    __syncthreads();
    const float tot  = rs[0] + rs[1] + rs[2] + rs[3];
    const float totq = rq[0] + rq[1] + rq[2] + rq[3];
    const float mu   = tot * (1.0f / D_MODEL);
    const float var  = totq * (1.0f / D_MODEL) - mu * mu;
    const float rstd = rsqrtf(var + 1e-5f);
    const float4 gv = ((const float4*)g)[tid];
    const float4 bv = ((const float4*)bb)[tid];
    unsigned short* o = lnout + (size_t)row * D_MODEL + tid * 4;
    o[0] = f2bf((v.x - mu) * rstd * gv.x + bv.x);
    o[1] = f2bf((v.y - mu) * rstd * gv.y + bv.y);
    o[2] = f2bf((v.z - mu) * rstd * gv.z + bv.z);
    o[3] = f2bf((v.w - mu) * rstd * gv.w + bv.w);
}

// ------------- proj split-K reduce: out += bias + p0 + p1 + p2 ------------------
__global__ __launch_bounds__(256) void reduce_kernel(float* __restrict__ out,
                                                     const unsigned short* __restrict__ pp,
                                                     const float* __restrict__ bias) {
    const int row = blockIdx.x;
    const int c0 = threadIdx.x * 4;
    const size_t base = (size_t)row * D_MODEL + c0;
    const size_t stride = (size_t)NROWS * D_MODEL;
    float4 o = *(float4*)(out + base);
    const float4 bs = *(const float4*)(bias + c0);
    o.x += bs.x; o.y += bs.y; o.z += bs.z; o.w += bs.w;
    #pragma unroll
    for (int z = 0; z < 3; ++z) {
        ushort4 a = *(const ushort4*)(pp + z * stride + base);
        o.x += bf2f(a.x); o.y += bf2f(a.y); o.z += bf2f(a.z); o.w += bf2f(a.w);
    }
    *(float4*)(out + base) = o;
}

// ---------------- Flash attention, causal, balanced (paired 128-q tiles) --------
__global__ __launch_bounds__(256) void attn_kernel(const unsigned short* __restrict__ qk,
                                                   const unsigned short* __restrict__ VT,
                                                   unsigned short* __restrict__ y) {
    __shared__ __align__(16) unsigned short Qs[128 * 64];
    __shared__ __align__(16) unsigned short Ks[64 * 64];
    __shared__ __align__(16) unsigned short Vs[80 * 64];
    __shared__ __align__(16) unsigned short Ps[128 * 68];

    const int tid  = threadIdx.x;
    const int lane = tid & 63, w = tid >> 6;
    const int quad = lane >> 4, l16 = lane & 15;
    const int s7   = l16 & 7;
    const int pc0  = (quad ^ s7) * 8;
    const int pc1  = ((quad + 4) ^ s7) * 8;
    const int srow = tid >> 3, sp = tid & 7;

    const int pairidx = blockIdx.x;
    const int bh = blockIdx.y;
    const int b = bh >> 4, h = bh & 15;
    const size_t rowbase = (size_t)b * SEQ;
    const unsigned short* Qbase = qk + h * 64;
    const unsigned short* Kbase = qk + 1024 + h * 64;
    const unsigned short* Vbase = VT + (size_t)(h * 64) * NROWS + b * SEQ;

    #pragma unroll
    for (int e = 0; e < 4; ++e) {
        const int off = tid * 4 + e;
        Vs[4096 + off] = (off < 64) ? (unsigned short)0x3F80 : (unsigned short)0;
    }

    for (int phase = 0; phase < 2; ++phase) {
        const int Q = phase ? pairidx : (15 - pairidx);
        const int nkt = 2 * Q + 2;
        const int qg0 = Q * 128;

        #pragma unroll
        for (int i = 0; i < 4; ++i) {
            const int row = i * 32 + srow;
            const int c = sp ^ (row & 7);
            ASYNC_COPY16(Qbase + (rowbase + qg0 + row) * 2048 + c * 8,
                         (char*)Qs + i * 4096 + tid * 16);
        }
        __syncthreads();

        bf16x8 aq[2][2];
        #pragma unroll
        for (int sub = 0; sub < 2; ++sub) {
            const int qrow = sub * 64 + w * 16 + l16;
            aq[sub][0] = *(const bf16x8*)&Qs[qrow * 64 + pc0];
            aq[sub][1] = *(const bf16x8*)&Qs[qrow * 64 + pc1];
        }

        f32x4 o[2][5] = {};

        for (int kt = 0; kt < nkt; ++kt) {
            #pragma unroll
            for (int i = 0; i < 2; ++i) {
                const int row = i * 32 + srow;
                const int c = sp ^ (row & 7);
                ASYNC_COPY16(Kbase + (rowbase + kt * 64 + row) * 2048 + c * 8,
                             (char*)Ks + i * 4096 + tid * 16);
                ASYNC_COPY16(Vbase + (size_t)row * NROWS + kt * 64 + c * 8,
                             (char*)Vs + i * 4096 + tid * 16);
            }
            __syncthreads();

            bf16x8 bk[4][2];
            #pragma unroll
            for (int cb = 0; cb < 4; ++cb) {
                const int krow = cb * 16 + l16;
                bk[cb][0] = *(const bf16x8*)&Ks[krow * 64 + pc0];
                bk[cb][1] = *(const bf16x8*)&Ks[krow * 64 + pc1];
            }

            #pragma unroll
            for (int sub = 0; sub < 2; ++sub) {
                if (kt > 2 * Q + sub) continue;
                f32x4 s[4] = {};
                #pragma unroll
                for (int cb = 0; cb < 4; ++cb) {
                    s[cb] = __builtin_amdgcn_mfma_f32_16x16x32_bf16(aq[sub][0], bk[cb][0], s[cb], 0, 0, 0);
                    s[cb] = __builtin_amdgcn_mfma_f32_16x16x32_bf16(aq[sub][1], bk[cb][1], s[cb], 0, 0, 0);
                }
                const int prow0 = sub * 64 + w * 16 + quad * 4;
                if (kt == 2 * Q + sub) {
                    const int qg = qg0 + prow0;
                    const int kg = kt * 64 + l16;
                    #pragma unroll
                    for (int cb = 0; cb < 4; ++cb)
                        #pragma unroll
                        for (int r = 0; r < 4; ++r) {
                            const float e = __expf(s[cb][r]);
                            const float pv = (kg + cb * 16 > qg + r) ? 0.0f : e;
                            Ps[(prow0 + r) * 68 + cb * 16 + l16] = f2bf(pv);
                        }
                } else {
                    #pragma unroll
                    for (int cb = 0; cb < 4; ++cb)
                        #pragma unroll
                        for (int r = 0; r < 4; ++r)
                            Ps[(prow0 + r) * 68 + cb * 16 + l16] = f2bf(__expf(s[cb][r]));
                }
            }
            __syncthreads();

            bf16x8 bv[5][2];
            #pragma unroll
            for (int db = 0; db < 5; ++db) {
                const int vrow = db * 16 + l16;
                bv[db][0] = *(const bf16x8*)&Vs[vrow * 64 + pc0];
                bv[db][1] = *(const bf16x8*)&Vs[vrow * 64 + pc1];
            }
            #pragma unroll
            for (int sub = 0; sub < 2; ++sub) {
                if (kt > 2 * Q + sub) continue;
                const unsigned short* pb = &Ps[(sub * 64 + w * 16 + l16) * 68];
                bf16x8 ap0, ap1;
                *(bf16x4*)&ap0       = *(const bf16x4*)(pb + quad * 8);
                *((bf16x4*)&ap0 + 1) = *(const bf16x4*)(pb + quad * 8 + 4);
                *(bf16x4*)&ap1       = *(const bf16x4*)(pb + 32 + quad * 8);
                *((bf16x4*)&ap1 + 1) = *(const bf16x4*)(pb + 32 + quad * 8 + 4);
                #pragma unroll
                for (int db = 0; db < 5; ++db) {
                    o[sub][db] = __builtin_amdgcn_mfma_f32_16x16x32_bf16(ap0, bv[db][0], o[sub][db], 0, 0, 0);
                    o[sub][db] = __builtin_amdgcn_mfma_f32_16x16x32_bf16(ap1, bv[db][1], o[sub][db], 0, 0, 0);
                }
            }
            __syncthreads();
        }

        #pragma unroll
        for (int sub = 0; sub < 2; ++sub)
            #pragma unroll
            for (int r = 0; r < 4; ++r) {
                const float lsum = __shfl(o[sub][4][r], lane & 48);
                const float rinv = 1.0f / lsum;
                const int trow = qg0 + sub * 64 + w * 16 + quad * 4 + r;
                unsigned short* yp = y + (rowbase + trow) * (size_t)D_MODEL + h * 64 + l16;
                #pragma unroll
                for (int db = 0; db < 4; ++db)
                    yp[db * 16] = f2bf(o[sub][db][r] * rinv);
            }
    }
}

extern "C" void kernel_launch(void* const* d_in, const int* in_sizes, int n_in,
                              void* d_out, int out_size, void* d_ws, size_t ws_size,
                              hipStream_t stream) {
    (void)in_sizes; (void)n_in; (void)out_size; (void)ws_size;
    const float* x      = (const float*)d_in[0];
    const float* w_attn = (const float*)d_in[1];
    const float* w_o    = (const float*)d_in[2];
    const float* ln1_g  = (const float*)d_in[3];
    const float* ln1_b  = (const float*)d_in[4];
    const float* ln2_g  = (const float*)d_in[5];
    const float* ln2_b  = (const float*)d_in[6];
    const float* w_fc   = (const float*)d_in[7];
    const float* b_fc   = (const float*)d_in[8];
    const float* w_proj = (const float*)d_in[9];
    const float* b_proj = (const float*)d_in[10];
    float* out = (float*)d_out;

    char* ws = (char*)d_ws;
    const size_t MiB = 1048576;
    // Memory map (MiB), phase-ordered (regions reused once dead):
    //  phase1: ln_buf@0..16 | qkbuf@16..48 | VTbuf@48..64 | wt_attn@64..70 | wt_o@126..128
    //  phase2 (post-attn): pw@16..80 (4x16)
    //  phase3 (post-reduce_wo): wt_fc@48..56 | wt_proj@56..64 | hbuf@64..128
    //  phase4 (post-fc): pp@0..48 (3x16)
    unsigned short* ln_buf  = (unsigned short*)ws;
    unsigned short* qkbuf   = (unsigned short*)(ws + 16 * MiB);
    unsigned short* VTbuf   = (unsigned short*)(ws + 48 * MiB);
    unsigned short* wt_attn = (unsigned short*)(ws + 64 * MiB);
    unsigned short* hbuf    = (unsigned short*)(ws + 64 * MiB);
    unsigned short* wt_o    = (unsigned short*)(ws + 126 * MiB);
    unsigned short* pw      = (unsigned short*)(ws + 16 * MiB);   // 4 x 16 MiB
    unsigned short* wt_fc   = (unsigned short*)(ws + 48 * MiB);
    unsigned short* wt_proj = (unsigned short*)(ws + 56 * MiB);
    unsigned short* pp      = (unsigned short*)ws;                // 3 x 16 MiB

    wt_kernel<<<dim3(3072 / 32, 1024 / 32), 256, 0, stream>>>(w_attn, wt_attn, 1024, 3072);
    wt_kernel<<<dim3(1024 / 32, 1024 / 32), 256, 0, stream>>>(w_o, wt_o, 1024, 1024);

    ln_kernel<<<NROWS, 256, 0, stream>>>(x, ln1_g, ln1_b, ln_buf);

    // merged QKV (m fast): Q(scaled)/K -> qkbuf, V -> VTbuf (transposed)
    gemm_qkv<<<dim3(NROWS / 128, 3072 / 128), 256, 0, stream>>>(
        ln_buf, wt_attn, qkbuf, VTbuf);

    attn_kernel<<<dim3(8, BATCH * NHEAD), 256, 0, stream>>>(qkbuf, VTbuf, ln_buf);

    // w_o: split-K=4 partials (m fast)
    gemm_bt<false, true, true><<<dim3(NROWS / 128, 1024 / 128, 4), 256, 0, stream>>>(
        ln_buf, wt_o, nullptr, nullptr, pw, NROWS, 1024, 1024, 256);
    // res1 = x + sum(pw) -> d_out ; LN2(res1) -> ln_buf
    reduce_wo_ln2<<<NROWS, 256, 0, stream>>>(x, pw, ln2_g, ln2_b, out, ln_buf);

    wt_kernel<<<dim3(4096 / 32, 1024 / 32), 256, 0, stream>>>(w_fc, wt_fc, 1024, 4096);
    wt_kernel<<<dim3(1024 / 32, 4096 / 32), 256, 0, stream>>>(w_proj, wt_proj, 4096, 1024);

    // fc: 256x128 dense tile (m fast), gelu+bias fused
    gemm_big<<<dim3(NROWS / 256, 4096 / 128), 256, 0, stream>>>(
        ln_buf, wt_fc, b_fc, hbuf, NROWS, 4096, 1024);

    // proj: split-K=3 partials (m fast; slices 1344/1344/1408), then reduce
    gemm_bt<false, true, true><<<dim3(NROWS / 128, 1024 / 128, 3), 256, 0, stream>>>(
        hbuf, wt_proj, nullptr, nullptr, pp, NROWS, 1024, 4096, 1344);
    reduce_kernel<<<NROWS, 256, 0, stream>>>(out, pp, b_proj);
}

// Round 8
// 513.931 us; speedup vs baseline: 1.2615x; 1.0630x over previous
//
#include <hip/hip_runtime.h>
#include <math.h>

#define D_MODEL 1024
#define NHEAD   16
#define HDIM    64
#define SEQ     2048
#define BATCH   4
#define NROWS   (BATCH*SEQ)   // 8192

using bf16x8 = __attribute__((ext_vector_type(8))) short;
using bf16x4 = __attribute__((ext_vector_type(4))) short;
using f32x4  = __attribute__((ext_vector_type(4))) float;

__device__ __forceinline__ unsigned short f2bf(float f) {
    unsigned u = __float_as_uint(f);
    u += 0x7fffu + ((u >> 16) & 1u);
    return (unsigned short)(u >> 16);
}
__device__ __forceinline__ float bf2f(unsigned short h) {
    unsigned u = ((unsigned)h) << 16;
    return __uint_as_float(u);
}

#define ASYNC_COPY16(g, l) \
    __builtin_amdgcn_global_load_lds((__attribute__((address_space(1))) const void*)(g), \
                                     (__attribute__((address_space(3))) void*)(l), 16, 0, 0)

// ---------------- LayerNorm (LN1): one block per row of 1024 --------------------
__global__ __launch_bounds__(256) void ln_kernel(const float* __restrict__ x,
                                                 const float* __restrict__ g,
                                                 const float* __restrict__ b,
                                                 unsigned short* __restrict__ out) {
    const int row = blockIdx.x;
    const int tid = threadIdx.x;
    const float4* x4 = (const float4*)(x + (size_t)row * D_MODEL);
    float4 v = x4[tid];
    float s  = v.x + v.y + v.z + v.w;
    float sq = v.x*v.x + v.y*v.y + v.z*v.z + v.w*v.w;
    #pragma unroll
    for (int off = 32; off >= 1; off >>= 1) {
        s  += __shfl_down(s,  off, 64);
        sq += __shfl_down(sq, off, 64);
    }
    __shared__ float rs[4], rq[4];
    const int wave = tid >> 6;
    if ((tid & 63) == 0) { rs[wave] = s; rq[wave] = sq; }
    __syncthreads();
    const float tot  = rs[0] + rs[1] + rs[2] + rs[3];
    const float totq = rq[0] + rq[1] + rq[2] + rq[3];
    const float mu   = tot * (1.0f / D_MODEL);
    const float var  = totq * (1.0f / D_MODEL) - mu * mu;
    const float rstd = rsqrtf(var + 1e-5f);
    const float4 gv = ((const float4*)g)[tid];
    const float4 bv = ((const float4*)b)[tid];
    unsigned short* o = out + (size_t)row * D_MODEL + tid * 4;
    o[0] = f2bf((v.x - mu) * rstd * gv.x + bv.x);
    o[1] = f2bf((v.y - mu) * rstd * gv.y + bv.y);
    o[2] = f2bf((v.z - mu) * rstd * gv.z + bv.z);
    o[3] = f2bf((v.w - mu) * rstd * gv.w + bv.w);
}

// ------------- Weight transpose+convert: w[K][N] f32 -> wt[N][K] bf16 -----------
__global__ __launch_bounds__(256) void wt_kernel(const float* __restrict__ w,
                                                 unsigned short* __restrict__ wt,
                                                 int K, int N) {
    __shared__ float tile[32][33];
    const int n0 = blockIdx.x * 32, k0 = blockIdx.y * 32;
    const int tx = threadIdx.x & 31, ty = threadIdx.x >> 5;
    #pragma unroll
    for (int j = 0; j < 4; ++j)
        tile[ty + j * 8][tx] = w[(size_t)(k0 + ty + j * 8) * N + n0 + tx];
    __syncthreads();
    #pragma unroll
    for (int j = 0; j < 4; ++j)
        wt[(size_t)(n0 + ty + j * 8) * K + k0 + tx] = f2bf(tile[tx][ty + j * 8]);
}

// ------------- GEMM 256x128, BK=64 (grid: x=m, y=n, [z=split]) ------------------
// 4 waves 2x2: wave covers 128 rows x 64 cols = 8x4 MFMAs x 2 k-halves.
// MODE 0: bias+gelu bf16 out (fc)
// MODE 1: bf16 partial to outp + z*M*N, split-K slices of Kslice (last extends)
// MODE 2: qkv dual-out (n0<1024: x0.125 -> qk; <2048: -> qk; else V^T store)
template<int MODE>
__global__ __launch_bounds__(256, 2) void gemm_big(const unsigned short* __restrict__ A,
                                                   const unsigned short* __restrict__ Bt,
                                                   const float* __restrict__ bias,
                                                   unsigned short* __restrict__ outp,
                                                   unsigned short* __restrict__ vt_out,
                                                   int M, int N, int K, int Kslice) {
    __shared__ __align__(16) unsigned short As[256 * 64];   // 32 KiB
    __shared__ __align__(16) unsigned short Bs[128 * 64];   // 16 KiB

    const int tid  = threadIdx.x;
    const int lane = tid & 63;
    const int wave = __builtin_amdgcn_readfirstlane(tid >> 6);
    const int quad = lane >> 4, l16 = lane & 15;
    const int wm = wave >> 1, wn = wave & 1;
    const int m0 = blockIdx.x * 256, n0 = blockIdx.y * 128;

    int kbeg = 0, klen = K;
    if (MODE == 1) {
        kbeg = blockIdx.z * Kslice;
        klen = (blockIdx.z == gridDim.z - 1) ? (K - kbeg) : Kslice;
    }

    f32x4 acc[8][4] = {};

    // staging: 12 DMA issues/thread/iter. issue i covers rows i*32+(tid>>3),
    // physical chunk tid&7 holds global chunk (tid&7)^(row&7).
    const int rr  = tid >> 3;                 // 0..31
    const int p   = tid & 7;
    const int gch = (p ^ (rr & 7)) * 8;       // swizzled global chunk (elements)

    const unsigned short* Ag[8];
    const unsigned short* Bg[4];
    #pragma unroll
    for (int i = 0; i < 8; ++i)
        Ag[i] = A + (size_t)(m0 + i * 32 + rr) * K + gch + kbeg;
    #pragma unroll
    for (int i = 0; i < 4; ++i)
        Bg[i] = Bt + (size_t)(n0 + i * 32 + rr) * K + gch + kbeg;

    // read-side: k-half 0 chunk = quad ^ (l16&7); half 1 = same ^ 4 (i.e. +-32 elems)
    const int pc = (quad ^ (l16 & 7)) * 8;

    for (int kb = 0; kb < klen; kb += 64) {
        #pragma unroll
        for (int i = 0; i < 8; ++i)
            ASYNC_COPY16(Ag[i] + kb, As + i * 2048 + tid * 8);
        #pragma unroll
        for (int i = 0; i < 4; ++i)
            ASYNC_COPY16(Bg[i] + kb, Bs + i * 2048 + tid * 8);
        __syncthreads();

        #pragma unroll
        for (int half = 0; half < 2; ++half) {
            const int off = half ? (pc ^ 32) : pc;
            bf16x8 b[4];
            #pragma unroll
            for (int j = 0; j < 4; ++j)
                b[j] = *(const bf16x8*)&Bs[(wn * 64 + j * 16 + l16) * 64 + off];
            #pragma unroll
            for (int i = 0; i < 8; ++i) {
                bf16x8 a = *(const bf16x8*)&As[(wm * 128 + i * 16 + l16) * 64 + off];
                #pragma unroll
                for (int j = 0; j < 4; ++j)
                    acc[i][j] = __builtin_amdgcn_mfma_f32_16x16x32_bf16(a, b[j], acc[i][j], 0, 0, 0);
            }
        }
        __syncthreads();
    }

    if (MODE == 0) {
        #pragma unroll
        for (int i = 0; i < 8; ++i)
          #pragma unroll
          for (int j = 0; j < 4; ++j)
            #pragma unroll
            for (int r = 0; r < 4; ++r) {
                const int row = m0 + wm * 128 + i * 16 + quad * 4 + r;
                const int col = n0 + wn * 64 + j * 16 + l16;
                float v = acc[i][j][r] + bias[col];
                const float u = 0.7978845608028654f * (v + 0.044715f * v * v * v);
                const float e = __expf(2.0f * u);
                v = 0.5f * v * (2.0f - 2.0f / (e + 1.0f));
                outp[(size_t)row * N + col] = f2bf(v);
            }
    } else if (MODE == 1) {
        unsigned short* outb = outp + (size_t)blockIdx.z * M * N;
        #pragma unroll
        for (int i = 0; i < 8; ++i)
          #pragma unroll
          for (int j = 0; j < 4; ++j)
            #pragma unroll
            for (int r = 0; r < 4; ++r) {
                const int row = m0 + wm * 128 + i * 16 + quad * 4 + r;
                const int col = n0 + wn * 64 + j * 16 + l16;
                outb[(size_t)row * N + col] = f2bf(acc[i][j][r]);
            }
    } else {
        if (n0 < 2048) {
            const float sc = (n0 < 1024) ? 0.125f : 1.0f;   // block never straddles 1024
            #pragma unroll
            for (int i = 0; i < 8; ++i)
              #pragma unroll
              for (int j = 0; j < 4; ++j)
                #pragma unroll
                for (int r = 0; r < 4; ++r) {
                    const int row = m0 + wm * 128 + i * 16 + quad * 4 + r;
                    const int col = n0 + wn * 64 + j * 16 + l16;
                    outp[(size_t)row * 2048 + col] = f2bf(acc[i][j][r] * sc);
                }
        } else {
            #pragma unroll
            for (int i = 0; i < 8; ++i)
              #pragma unroll
              for (int j = 0; j < 4; ++j) {
                    const int dv  = n0 - 2048 + wn * 64 + j * 16 + l16;
                    const int tok = m0 + wm * 128 + i * 16 + quad * 4;
                    ushort4 pk;
                    pk.x = f2bf(acc[i][j][0]); pk.y = f2bf(acc[i][j][1]);
                    pk.z = f2bf(acc[i][j][2]); pk.w = f2bf(acc[i][j][3]);
                    *(ushort4*)(vt_out + (size_t)dv * NROWS + tok) = pk;
                }
        }
    }
}

// ------------- GEMM 128x128, BK=32 (w_o split-K path) ---------------------------
template<bool PARTIAL>
__global__ __launch_bounds__(256) void gemm_bt(const unsigned short* __restrict__ A,
                                               const unsigned short* __restrict__ Bt,
                                               unsigned short* __restrict__ outb,
                                               int M, int N, int K, int Kslice) {
    __shared__ __align__(16) unsigned short As[128 * 32];
    __shared__ __align__(16) unsigned short Bs[128 * 32];

    const int tid  = threadIdx.x;
    const int lane = tid & 63;
    const int wave = __builtin_amdgcn_readfirstlane(tid >> 6);
    const int quad = lane >> 4, l16 = lane & 15;
    const int wm = wave >> 1, wn = wave & 1;
    const int m0 = blockIdx.x * 128, n0 = blockIdx.y * 128;
    const int kbeg = PARTIAL ? blockIdx.z * Kslice : 0;
    const int klen = PARTIAL ? ((blockIdx.z == gridDim.z - 1) ? (K - kbeg) : Kslice) : K;

    f32x4 acc[4][4] = {};

    const int rA = tid >> 2;
    const int p  = tid & 3;
    const int cs = (p ^ ((rA >> 1) & 3)) * 8;

    const unsigned short* Ag0 = A  + (size_t)(m0 + rA) * K + cs + kbeg;
    const unsigned short* Ag1 = A  + (size_t)(m0 + rA + 64) * K + cs + kbeg;
    const unsigned short* Bg0 = Bt + (size_t)(n0 + rA) * K + cs + kbeg;
    const unsigned short* Bg1 = Bt + (size_t)(n0 + rA + 64) * K + cs + kbeg;
    unsigned short* Al0 = As + tid * 8;
    unsigned short* Al1 = As + tid * 8 + 2048;
    unsigned short* Bl0 = Bs + tid * 8;
    unsigned short* Bl1 = Bs + tid * 8 + 2048;

    const int sw = (quad ^ ((l16 >> 1) & 3)) * 8;

    for (int kb = 0; kb < klen; kb += 32) {
        ASYNC_COPY16(Ag0 + kb, Al0);
        ASYNC_COPY16(Ag1 + kb, Al1);
        ASYNC_COPY16(Bg0 + kb, Bl0);
        ASYNC_COPY16(Bg1 + kb, Bl1);
        __syncthreads();

        bf16x8 a[4], b[4];
        #pragma unroll
        for (int i = 0; i < 4; ++i)
            a[i] = *(const bf16x8*)&As[(wm * 64 + i * 16 + l16) * 32 + sw];
        #pragma unroll
        for (int j = 0; j < 4; ++j)
            b[j] = *(const bf16x8*)&Bs[(wn * 64 + j * 16 + l16) * 32 + sw];
        #pragma unroll
        for (int i = 0; i < 4; ++i)
            #pragma unroll
            for (int j = 0; j < 4; ++j)
                acc[i][j] = __builtin_amdgcn_mfma_f32_16x16x32_bf16(a[i], b[j], acc[i][j], 0, 0, 0);
        __syncthreads();
    }

    unsigned short* ob = outb;
    if (PARTIAL) ob += (size_t)blockIdx.z * M * N;

    #pragma unroll
    for (int i = 0; i < 4; ++i)
      #pragma unroll
      for (int j = 0; j < 4; ++j)
        #pragma unroll
        for (int r = 0; r < 4; ++r) {
            const int row = m0 + wm * 64 + i * 16 + quad * 4 + r;
            const int col = n0 + wn * 64 + j * 16 + l16;
            ob[(size_t)row * N + col] = f2bf(acc[i][j][r]);
        }
}

// ------- fused w_o reduce: res1 = x + p0..p3 -> d_out(f32); LN2(res1) -> lnout --
__global__ __launch_bounds__(256) void reduce_wo_ln2(const float* __restrict__ x,
                                                     const unsigned short* __restrict__ pw,
                                                     const float* __restrict__ g,
                                                     const float* __restrict__ bb,
                                                     float* __restrict__ out,
                                                     unsigned short* __restrict__ lnout) {
    const int row = blockIdx.x;
    const int tid = threadIdx.x;
    const size_t base = (size_t)row * D_MODEL + tid * 4;
    const size_t stride = (size_t)NROWS * D_MODEL;
    float4 v = *(const float4*)(x + base);
    #pragma unroll
    for (int z = 0; z < 4; ++z) {
        ushort4 a = *(const ushort4*)(pw + z * stride + base);
        v.x += bf2f(a.x); v.y += bf2f(a.y); v.z += bf2f(a.z); v.w += bf2f(a.w);
    }
    *(float4*)(out + base) = v;

    float s  = v.x + v.y + v.z + v.w;
    float sq = v.x*v.x + v.y*v.y + v.z*v.z + v.w*v.w;
    #pragma unroll
    for (int off = 32; off >= 1; off >>= 1) {
        s  += __shfl_down(s,  off, 64);
        sq += __shfl_down(sq, off, 64);
    }
    __shared__ float rs[4], rq[4];
    const int wave = tid >> 6;
    if ((tid & 63) == 0) { rs[wave] = s; rq[wave] = sq; }
    __syncthreads();
    const float tot  = rs[0] + rs[1] + rs[2] + rs[3];
    const float totq = rq[0] + rq[1] + rq[2] + rq[3];
    const float mu   = tot * (1.0f / D_MODEL);
    const float var  = totq * (1.0f / D_MODEL) - mu * mu;
    const float rstd = rsqrtf(var + 1e-5f);
    const float4 gv = ((const float4*)g)[tid];
    const float4 bv = ((const float4*)bb)[tid];
    unsigned short* o = lnout + (size_t)row * D_MODEL + tid * 4;
    o[0] = f2bf((v.x - mu) * rstd * gv.x + bv.x);
    o[1] = f2bf((v.y - mu) * rstd * gv.y + bv.y);
    o[2] = f2bf((v.z - mu) * rstd * gv.z + bv.z);
    o[3] = f2bf((v.w - mu) * rstd * gv.w + bv.w);
}

// ------------- proj split-K reduce: out += bias + p0 + p1 + p2 ------------------
__global__ __launch_bounds__(256) void reduce_kernel(float* __restrict__ out,
                                                     const unsigned short* __restrict__ pp,
                                                     const float* __restrict__ bias) {
    const int row = blockIdx.x;
    const int c0 = threadIdx.x * 4;
    const size_t base = (size_t)row * D_MODEL + c0;
    const size_t stride = (size_t)NROWS * D_MODEL;
    float4 o = *(float4*)(out + base);
    const float4 bs = *(const float4*)(bias + c0);
    o.x += bs.x; o.y += bs.y; o.z += bs.z; o.w += bs.w;
    #pragma unroll
    for (int z = 0; z < 3; ++z) {
        ushort4 a = *(const ushort4*)(pp + z * stride + base);
        o.x += bf2f(a.x); o.y += bf2f(a.y); o.z += bf2f(a.z); o.w += bf2f(a.w);
    }
    *(float4*)(out + base) = o;
}

// ---------------- Flash attention, causal, balanced (paired 128-q tiles) --------
__global__ __launch_bounds__(256) void attn_kernel(const unsigned short* __restrict__ qk,
                                                   const unsigned short* __restrict__ VT,
                                                   unsigned short* __restrict__ y) {
    __shared__ __align__(16) unsigned short Qs[128 * 64];
    __shared__ __align__(16) unsigned short Ks[64 * 64];
    __shared__ __align__(16) unsigned short Vs[80 * 64];
    __shared__ __align__(16) unsigned short Ps[128 * 68];

    const int tid  = threadIdx.x;
    const int lane = tid & 63, w = tid >> 6;
    const int quad = lane >> 4, l16 = lane & 15;
    const int s7   = l16 & 7;
    const int pc0  = (quad ^ s7) * 8;
    const int pc1  = ((quad + 4) ^ s7) * 8;
    const int srow = tid >> 3, sp = tid & 7;

    const int pairidx = blockIdx.x;
    const int bh = blockIdx.y;
    const int b = bh >> 4, h = bh & 15;
    const size_t rowbase = (size_t)b * SEQ;
    const unsigned short* Qbase = qk + h * 64;
    const unsigned short* Kbase = qk + 1024 + h * 64;
    const unsigned short* Vbase = VT + (size_t)(h * 64) * NROWS + b * SEQ;

    #pragma unroll
    for (int e = 0; e < 4; ++e) {
        const int off = tid * 4 + e;
        Vs[4096 + off] = (off < 64) ? (unsigned short)0x3F80 : (unsigned short)0;
    }

    for (int phase = 0; phase < 2; ++phase) {
        const int Q = phase ? pairidx : (15 - pairidx);
        const int nkt = 2 * Q + 2;
        const int qg0 = Q * 128;

        #pragma unroll
        for (int i = 0; i < 4; ++i) {
            const int row = i * 32 + srow;
            const int c = sp ^ (row & 7);
            ASYNC_COPY16(Qbase + (rowbase + qg0 + row) * 2048 + c * 8,
                         (char*)Qs + i * 4096 + tid * 16);
        }
        __syncthreads();

        bf16x8 aq[2][2];
        #pragma unroll
        for (int sub = 0; sub < 2; ++sub) {
            const int qrow = sub * 64 + w * 16 + l16;
            aq[sub][0] = *(const bf16x8*)&Qs[qrow * 64 + pc0];
            aq[sub][1] = *(const bf16x8*)&Qs[qrow * 64 + pc1];
        }

        f32x4 o[2][5] = {};

        for (int kt = 0; kt < nkt; ++kt) {
            #pragma unroll
            for (int i = 0; i < 2; ++i) {
                const int row = i * 32 + srow;
                const int c = sp ^ (row & 7);
                ASYNC_COPY16(Kbase + (rowbase + kt * 64 + row) * 2048 + c * 8,
                             (char*)Ks + i * 4096 + tid * 16);
                ASYNC_COPY16(Vbase + (size_t)row * NROWS + kt * 64 + c * 8,
                             (char*)Vs + i * 4096 + tid * 16);
            }
            __syncthreads();

            bf16x8 bk[4][2];
            #pragma unroll
            for (int cb = 0; cb < 4; ++cb) {
                const int krow = cb * 16 + l16;
                bk[cb][0] = *(const bf16x8*)&Ks[krow * 64 + pc0];
                bk[cb][1] = *(const bf16x8*)&Ks[krow * 64 + pc1];
            }

            #pragma unroll
            for (int sub = 0; sub < 2; ++sub) {
                if (kt > 2 * Q + sub) continue;
                f32x4 s[4] = {};
                #pragma unroll
                for (int cb = 0; cb < 4; ++cb) {
                    s[cb] = __builtin_amdgcn_mfma_f32_16x16x32_bf16(aq[sub][0], bk[cb][0], s[cb], 0, 0, 0);
                    s[cb] = __builtin_amdgcn_mfma_f32_16x16x32_bf16(aq[sub][1], bk[cb][1], s[cb], 0, 0, 0);
                }
                const int prow0 = sub * 64 + w * 16 + quad * 4;
                if (kt == 2 * Q + sub) {
                    const int qg = qg0 + prow0;
                    const int kg = kt * 64 + l16;
                    #pragma unroll
                    for (int cb = 0; cb < 4; ++cb)
                        #pragma unroll
                        for (int r = 0; r < 4; ++r) {
                            const float e = __expf(s[cb][r]);
                            const float pv = (kg + cb * 16 > qg + r) ? 0.0f : e;
                            Ps[(prow0 + r) * 68 + cb * 16 + l16] = f2bf(pv);
                        }
                } else {
                    #pragma unroll
                    for (int cb = 0; cb < 4; ++cb)
                        #pragma unroll
                        for (int r = 0; r < 4; ++r)
                            Ps[(prow0 + r) * 68 + cb * 16 + l16] = f2bf(__expf(s[cb][r]));
                }
            }
            __syncthreads();

            bf16x8 bv[5][2];
            #pragma unroll
            for (int db = 0; db < 5; ++db) {
                const int vrow = db * 16 + l16;
                bv[db][0] = *(const bf16x8*)&Vs[vrow * 64 + pc0];
                bv[db][1] = *(const bf16x8*)&Vs[vrow * 64 + pc1];
            }
            #pragma unroll
            for (int sub = 0; sub < 2; ++sub) {
                if (kt > 2 * Q + sub) continue;
                const unsigned short* pb = &Ps[(sub * 64 + w * 16 + l16) * 68];
                bf16x8 ap0, ap1;
                *(bf16x4*)&ap0       = *(const bf16x4*)(pb + quad * 8);
                *((bf16x4*)&ap0 + 1) = *(const bf16x4*)(pb + quad * 8 + 4);
                *(bf16x4*)&ap1       = *(const bf16x4*)(pb + 32 + quad * 8);
                *((bf16x4*)&ap1 + 1) = *(const bf16x4*)(pb + 32 + quad * 8 + 4);
                #pragma unroll
                for (int db = 0; db < 5; ++db) {
                    o[sub][db] = __builtin_amdgcn_mfma_f32_16x16x32_bf16(ap0, bv[db][0], o[sub][db], 0, 0, 0);
                    o[sub][db] = __builtin_amdgcn_mfma_f32_16x16x32_bf16(ap1, bv[db][1], o[sub][db], 0, 0, 0);
                }
            }
            __syncthreads();
        }

        #pragma unroll
        for (int sub = 0; sub < 2; ++sub)
            #pragma unroll
            for (int r = 0; r < 4; ++r) {
                const float lsum = __shfl(o[sub][4][r], lane & 48);
                const float rinv = 1.0f / lsum;
                const int trow = qg0 + sub * 64 + w * 16 + quad * 4 + r;
                unsigned short* yp = y + (rowbase + trow) * (size_t)D_MODEL + h * 64 + l16;
                #pragma unroll
                for (int db = 0; db < 4; ++db)
                    yp[db * 16] = f2bf(o[sub][db][r] * rinv);
            }
    }
}

extern "C" void kernel_launch(void* const* d_in, const int* in_sizes, int n_in,
                              void* d_out, int out_size, void* d_ws, size_t ws_size,
                              hipStream_t stream) {
    (void)in_sizes; (void)n_in; (void)out_size; (void)ws_size;
    const float* x      = (const float*)d_in[0];
    const float* w_attn = (const float*)d_in[1];
    const float* w_o    = (const float*)d_in[2];
    const float* ln1_g  = (const float*)d_in[3];
    const float* ln1_b  = (const float*)d_in[4];
    const float* ln2_g  = (const float*)d_in[5];
    const float* ln2_b  = (const float*)d_in[6];
    const float* w_fc   = (const float*)d_in[7];
    const float* b_fc   = (const float*)d_in[8];
    const float* w_proj = (const float*)d_in[9];
    const float* b_proj = (const float*)d_in[10];
    float* out = (float*)d_out;

    char* ws = (char*)d_ws;
    const size_t MiB = 1048576;
    // Memory map (MiB), phase-ordered:
    //  phase1: ln_buf@0..16 | qkbuf@16..48 | VTbuf@48..64 | wt_attn@64..70 | wt_o@126..128
    //  phase2 (post-attn): pw@16..80 (4x16)
    //  phase3 (post-reduce_wo): wt_fc@48..56 | wt_proj@56..64 | hbuf@64..128
    //  phase4 (post-fc): pp@0..48 (3x16)
    unsigned short* ln_buf  = (unsigned short*)ws;
    unsigned short* qkbuf   = (unsigned short*)(ws + 16 * MiB);
    unsigned short* VTbuf   = (unsigned short*)(ws + 48 * MiB);
    unsigned short* wt_attn = (unsigned short*)(ws + 64 * MiB);
    unsigned short* hbuf    = (unsigned short*)(ws + 64 * MiB);
    unsigned short* wt_o    = (unsigned short*)(ws + 126 * MiB);
    unsigned short* pw      = (unsigned short*)(ws + 16 * MiB);   // 4 x 16 MiB
    unsigned short* wt_fc   = (unsigned short*)(ws + 48 * MiB);
    unsigned short* wt_proj = (unsigned short*)(ws + 56 * MiB);
    unsigned short* pp      = (unsigned short*)ws;                // 3 x 16 MiB

    wt_kernel<<<dim3(3072 / 32, 1024 / 32), 256, 0, stream>>>(w_attn, wt_attn, 1024, 3072);
    wt_kernel<<<dim3(1024 / 32, 1024 / 32), 256, 0, stream>>>(w_o, wt_o, 1024, 1024);

    ln_kernel<<<NROWS, 256, 0, stream>>>(x, ln1_g, ln1_b, ln_buf);

    // merged QKV (256x128 BK=64): Q(scaled)/K -> qkbuf, V -> VTbuf (transposed)
    gemm_big<2><<<dim3(NROWS / 256, 3072 / 128), 256, 0, stream>>>(
        ln_buf, wt_attn, nullptr, qkbuf, VTbuf, NROWS, 3072, 1024, 0);

    attn_kernel<<<dim3(8, BATCH * NHEAD), 256, 0, stream>>>(qkbuf, VTbuf, ln_buf);

    // w_o: split-K=4 partials (128x128 BK=32, m fast)
    gemm_bt<true><<<dim3(NROWS / 128, 1024 / 128, 4), 256, 0, stream>>>(
        ln_buf, wt_o, pw, NROWS, 1024, 1024, 256);
    // res1 = x + sum(pw) -> d_out ; LN2(res1) -> ln_buf
    reduce_wo_ln2<<<NROWS, 256, 0, stream>>>(x, pw, ln2_g, ln2_b, out, ln_buf);

    wt_kernel<<<dim3(4096 / 32, 1024 / 32), 256, 0, stream>>>(w_fc, wt_fc, 1024, 4096);
    wt_kernel<<<dim3(1024 / 32, 4096 / 32), 256, 0, stream>>>(w_proj, wt_proj, 4096, 1024);

    // fc: 256x128 BK=64, gelu+bias fused
    gemm_big<0><<<dim3(NROWS / 256, 4096 / 128), 256, 0, stream>>>(
        ln_buf, wt_fc, b_fc, hbuf, nullptr, NROWS, 4096, 1024, 0);

    // proj: 256x128 BK=64, split-K=3 (slices 1344/1344/1408), then reduce
    gemm_big<1><<<dim3(NROWS / 256, 1024 / 128, 3), 256, 0, stream>>>(
        hbuf, wt_proj, nullptr, pp, nullptr, NROWS, 1024, 4096, 1344);
    reduce_kernel<<<NROWS, 256, 0, stream>>>(out, pp, b_proj);
}